// Round 2
// baseline (565.578 us; speedup 1.0000x reference)
//
#include <hip/hip_runtime.h>
#include <hip/hip_bf16.h>

typedef __attribute__((ext_vector_type(8))) short bf16x8;
typedef __attribute__((ext_vector_type(4))) float f32x4;

#define NB 2048
#define TT 128   // T-1
#define FF 128
#define HH 128
#define NG 512   // 4*H
#define CHUNK 32
#define NCHUNK 4

__device__ __forceinline__ unsigned short f2bf(float x) {
  union { float f; unsigned u; } v; v.f = x;
  unsigned r = (v.u + 0x7fffu + ((v.u >> 16) & 1u)) >> 16;
  return (unsigned short)r;
}
__device__ __forceinline__ float bf2f(unsigned short u) {
  union { unsigned u; float f; } v; v.u = ((unsigned)u) << 16;
  return v.f;
}
__device__ __forceinline__ float sigf(float x) { return 1.f / (1.f + __expf(-x)); }
__device__ __forceinline__ float tanh_(float x) {
  float e = __expf(-2.f * x);
  return (1.f - e) / (1.f + e);
}
// XOR swizzle for 256B (128 bf16) rows: spreads 16B chunks across banks
__device__ __forceinline__ unsigned swzb(int row, int kbyte) {
  return (unsigned)(row * 256 + (kbyte ^ ((row & 7) << 4)));
}

// ---------------- K0: prep (w_ih -> bf16, bias = b_ih + b_hh) ----------------
__global__ void k_prep(const float* __restrict__ w_ih, const float* __restrict__ b_ih,
                       const float* __restrict__ b_hh, unsigned short* __restrict__ wihb,
                       float* __restrict__ bias) {
  int g = blockIdx.x * blockDim.x + threadIdx.x;
  int gs = gridDim.x * blockDim.x;
  for (int i = g; i < NG * FF; i += gs) wihb[i] = f2bf(w_ih[i]);
  if (g < NG) bias[g] = b_ih[g] + b_hh[g];
}

// ---------------- K1: a[b,f] = softmax_f( sum_t x[b,t,f]*wx[t] ) -------------
__global__ void k_attn(const float* __restrict__ x, const float* __restrict__ w_lin,
                       float* __restrict__ a_out) {
  __shared__ float wx[TT];
  __shared__ float red[4];
  int b = blockIdx.x;
  int f = threadIdx.x;           // 128 threads
  wx[f] = w_lin[2 * HH + f];     // wx = w_lin[0, 256:384]
  __syncthreads();
  const float* xb = x + (size_t)b * TT * FF + f;
  float s = 0.f;
#pragma unroll 8
  for (int t = 0; t < TT; ++t) s += xb[(size_t)t * FF] * wx[t];
  // softmax across 128 threads (2 waves)
  float m = s;
#pragma unroll
  for (int d = 1; d < 64; d <<= 1) m = fmaxf(m, __shfl_xor(m, d));
  int wv = f >> 6;
  if ((f & 63) == 0) red[wv] = m;
  __syncthreads();
  m = fmaxf(red[0], red[1]);
  float e = __expf(s - m);
  float sum = e;
#pragma unroll
  for (int d = 1; d < 64; d <<= 1) sum += __shfl_xor(sum, d);
  if ((f & 63) == 0) red[2 + wv] = sum;
  __syncthreads();
  sum = red[2] + red[3];
  a_out[(size_t)b * FF + f] = e / sum;
}

// ---------------- K2: x_atn = a * x  (f32 out) -------------------------------
__global__ void k_xatn(const float* __restrict__ x, const float* __restrict__ a,
                       float* __restrict__ out) {
  size_t stride = (size_t)gridDim.x * blockDim.x;
  size_t n4 = (size_t)NB * TT * FF / 4;
  for (size_t i4 = (size_t)blockIdx.x * blockDim.x + threadIdx.x; i4 < n4; i4 += stride) {
    size_t i = i4 * 4;
    float4 xv = ((const float4*)x)[i4];
    int f0 = (int)(i & (FF - 1));
    size_t b = i >> 14;          // / (TT*FF)
    float4 av = *(const float4*)(a + b * FF + f0);
    float4 o;
    o.x = xv.x * av.x;
    o.y = xv.y * av.y;
    o.z = xv.z * av.z;
    o.w = xv.w * av.w;
    ((float4*)out)[i4] = o;
  }
}

// ---------------- K3: gates_x chunk GEMM: (2048*32 x 128) @ (128 x 512) ------
__global__ __launch_bounds__(256) void k_gx(const float* __restrict__ xa,
                                            const unsigned short* __restrict__ wihb,
                                            const float* __restrict__ bias,
                                            unsigned short* __restrict__ gx, int t0) {
  __shared__ unsigned char aLds[32 * 256];
  int tid = threadIdx.x;
  int m0 = blockIdx.x * 32;
  // stage A tile (32 rows x 128 bf16, converted from f32 x_atn), swizzled
  for (int cc = tid; cc < 512; cc += 256) {
    int row = cc >> 4, c16 = cc & 15;
    int rg = m0 + row;
    int b = rg >> 5, tl = rg & 31;
    const float* src = xa + ((size_t)b * TT + t0 + tl) * FF + c16 * 8;
    float4 v0 = *(const float4*)src;
    float4 v1 = *(const float4*)(src + 4);
    unsigned p0 = (unsigned)f2bf(v0.x) | ((unsigned)f2bf(v0.y) << 16);
    unsigned p1 = (unsigned)f2bf(v0.z) | ((unsigned)f2bf(v0.w) << 16);
    unsigned p2 = (unsigned)f2bf(v1.x) | ((unsigned)f2bf(v1.y) << 16);
    unsigned p3 = (unsigned)f2bf(v1.z) | ((unsigned)f2bf(v1.w) << 16);
    uint4 pk; pk.x = p0; pk.y = p1; pk.z = p2; pk.w = p3;
    *(uint4*)(aLds + swzb(row, c16 * 16)) = pk;
  }
  __syncthreads();
  int l = tid & 63, w = tid >> 6;
  int lg = l >> 4;
  bf16x8 A[2][4];
#pragma unroll
  for (int mt = 0; mt < 2; ++mt)
#pragma unroll
    for (int ks = 0; ks < 4; ++ks)
      A[mt][ks] = *(const bf16x8*)(aLds + swzb(mt * 16 + (l & 15), ks * 64 + lg * 16));
#pragma unroll
  for (int ntw = 0; ntw < 8; ++ntw) {
    int nt = w * 8 + ntw;
    int col = nt * 16 + (l & 15);
    bf16x8 B[4];
#pragma unroll
    for (int ks = 0; ks < 4; ++ks)
      B[ks] = *(const bf16x8*)(wihb + (size_t)col * FF + ks * 32 + lg * 8);
    float bc = bias[col];
#pragma unroll
    for (int mt = 0; mt < 2; ++mt) {
      f32x4 acc = {0.f, 0.f, 0.f, 0.f};
#pragma unroll
      for (int ks = 0; ks < 4; ++ks)
        acc = __builtin_amdgcn_mfma_f32_16x16x32_bf16(A[mt][ks], B[ks], acc, 0, 0, 0);
      int rb = m0 + mt * 16 + lg * 4;
#pragma unroll
      for (int r = 0; r < 4; ++r)
        gx[(size_t)(rb + r) * NG + col] = f2bf(acc[r] + bc);
    }
  }
}

// ---------------- K4: recurrence, 8 batch rows / block, 8 waves --------------
__global__ __launch_bounds__(512) void k_rnn(const float* __restrict__ w_hh,
                                             const unsigned short* __restrict__ gx,
                                             float* __restrict__ enc,
                                             float* __restrict__ h_state,
                                             float* __restrict__ c_state, int t0) {
  __shared__ unsigned char hLds[16 * 256];  // 16 rows x 128 bf16 (rows 8..15 zero pad)
  int tid = threadIdx.x;
  int l = tid & 63, w = tid >> 6;
  int lg = l >> 4;
  int b0 = blockIdx.x * 8;
  int kl = w * 16 + (l & 15);  // this lane's gate column k in [0,128)
  // B-fragments of w_hh for the 4 gates (i,f,g,o), constant across steps
  bf16x8 Bf[4][4];
#pragma unroll
  for (int g = 0; g < 4; ++g) {
    int n = (g * 8 + w) * 16 + (l & 15);  // column g*128 + kl of the 512
#pragma unroll
    for (int ks = 0; ks < 4; ++ks) {
      const float* p = w_hh + (size_t)n * HH + ks * 32 + lg * 8;
      float4 v0 = *(const float4*)p;
      float4 v1 = *(const float4*)(p + 4);
      bf16x8 bb;
      bb[0] = (short)f2bf(v0.x); bb[1] = (short)f2bf(v0.y);
      bb[2] = (short)f2bf(v0.z); bb[3] = (short)f2bf(v0.w);
      bb[4] = (short)f2bf(v1.x); bb[5] = (short)f2bf(v1.y);
      bb[6] = (short)f2bf(v1.z); bb[7] = (short)f2bf(v1.w);
      Bf[g][ks] = bb;
    }
  }
  for (int i = tid; i < 1024; i += 512) ((unsigned*)hLds)[i] = 0u;
  __syncthreads();
  bool act = (lg < 2);       // lanes holding valid C rows (b rows 0..7)
  int brow = lg * 4;
  float c[4] = {0.f, 0.f, 0.f, 0.f};
  if (t0 > 0) {
    if (act) {
#pragma unroll
      for (int r = 0; r < 4; ++r)
        c[r] = c_state[(size_t)(b0 + brow + r) * HH + kl];
    }
    // stage h state into swizzled LDS (rows 0..7)
    int row = tid >> 6, k2 = (tid & 63) * 2;
    float h0 = h_state[(size_t)(b0 + row) * HH + k2];
    float h1 = h_state[(size_t)(b0 + row) * HH + k2 + 1];
    unsigned pk = (unsigned)f2bf(h0) | ((unsigned)f2bf(h1) << 16);
    *(unsigned*)(hLds + swzb(row, k2 * 2)) = pk;
  }
  __syncthreads();
  for (int tl = 0; tl < CHUNK; ++tl) {
    int t = t0 + tl;
    // prefetch gates_x for this step (global, hidden under ds_reads/MFMA)
    unsigned short gxv[4][4];
    if (act) {
#pragma unroll
      for (int r = 0; r < 4; ++r) {
        size_t rowg = ((size_t)(b0 + brow + r) * CHUNK + tl) * NG;
#pragma unroll
        for (int g = 0; g < 4; ++g) gxv[r][g] = gx[rowg + (size_t)g * 128 + kl];
      }
    }
    // A-fragments of h (all lanes supply rows 0..15; rows 8..15 are zeros)
    bf16x8 Af[4];
#pragma unroll
    for (int ks = 0; ks < 4; ++ks)
      Af[ks] = *(const bf16x8*)(hLds + swzb(l & 15, ks * 64 + lg * 16));
    __syncthreads();  // all A reads done before h writes below
    f32x4 ai = {0.f,0.f,0.f,0.f}, af = {0.f,0.f,0.f,0.f};
    f32x4 ag = {0.f,0.f,0.f,0.f}, ao = {0.f,0.f,0.f,0.f};
#pragma unroll
    for (int ks = 0; ks < 4; ++ks) {
      ai = __builtin_amdgcn_mfma_f32_16x16x32_bf16(Af[ks], Bf[0][ks], ai, 0, 0, 0);
      af = __builtin_amdgcn_mfma_f32_16x16x32_bf16(Af[ks], Bf[1][ks], af, 0, 0, 0);
      ag = __builtin_amdgcn_mfma_f32_16x16x32_bf16(Af[ks], Bf[2][ks], ag, 0, 0, 0);
      ao = __builtin_amdgcn_mfma_f32_16x16x32_bf16(Af[ks], Bf[3][ks], ao, 0, 0, 0);
    }
    if (act) {
#pragma unroll
      for (int r = 0; r < 4; ++r) {
        int bg = b0 + brow + r;
        float gi = ai[r] + bf2f(gxv[r][0]);
        float gf = af[r] + bf2f(gxv[r][1]);
        float gg = ag[r] + bf2f(gxv[r][2]);
        float go = ao[r] + bf2f(gxv[r][3]);
        float cn = sigf(gf) * c[r] + sigf(gi) * tanh_(gg);
        c[r] = cn;
        float hv = sigf(go) * tanh_(cn);
        enc[((size_t)bg * TT + t) * HH + kl] = hv;
        *(unsigned short*)(hLds + swzb(brow + r, kl * 2)) = f2bf(hv);
        if (tl == CHUNK - 1) {
          h_state[(size_t)bg * HH + kl] = hv;
          c_state[(size_t)bg * HH + kl] = cn;
        }
      }
    }
    __syncthreads();
  }
}

extern "C" void kernel_launch(void* const* d_in, const int* in_sizes, int n_in,
                              void* d_out, int out_size, void* d_ws, size_t ws_size,
                              hipStream_t stream) {
  (void)in_sizes; (void)n_in; (void)out_size; (void)ws_size;
  const float* x     = (const float*)d_in[0];
  const float* w_lin = (const float*)d_in[1];
  const float* w_ih  = (const float*)d_in[3];
  const float* w_hh  = (const float*)d_in[4];
  const float* b_ih  = (const float*)d_in[5];
  const float* b_hh  = (const float*)d_in[6];
  float* out = (float*)d_out;  // f32 outputs: [x_atn (2048*128*128) | x_enc (2048*128*128)]

  char* ws = (char*)d_ws;
  float* a            = (float*)(ws);                                   // 1 MB
  float* bias         = (float*)(ws + (1 << 20));                       // 2 KB
  unsigned short* wihb = (unsigned short*)(ws + (1 << 20) + 4096);      // 128 KB
  float* h_state      = (float*)(ws + (1 << 20) + 4096 + (1 << 17));    // 1 MB
  float* c_state      = (float*)(ws + (2 << 20) + 4096 + (1 << 17));    // 1 MB
  unsigned short* gxb = (unsigned short*)(ws + ((size_t)4 << 20));      // 64 MB

  float* enc = out + (size_t)NB * TT * FF;  // second output

  k_prep<<<dim3(64), dim3(256), 0, stream>>>(w_ih, b_ih, b_hh, wihb, bias);
  k_attn<<<dim3(NB), dim3(128), 0, stream>>>(x, w_lin, a);
  k_xatn<<<dim3(2048), dim3(256), 0, stream>>>(x, a, out);
  for (int cidx = 0; cidx < NCHUNK; ++cidx) {
    k_gx<<<dim3(2048), dim3(256), 0, stream>>>(out, wihb, bias, gxb, cidx * CHUNK);
    k_rnn<<<dim3(256), dim3(512), 0, stream>>>(w_hh, gxb, enc, h_state, c_state, cidx * CHUNK);
  }
}

// Round 3
// 264.650 us; speedup vs baseline: 2.1371x; 2.1371x over previous
//
#include <hip/hip_runtime.h>
#include <hip/hip_bf16.h>

typedef __attribute__((ext_vector_type(8))) short bf16x8;
typedef __attribute__((ext_vector_type(4))) float f32x4;

#define NB 2048
#define TT 128   // T-1
#define FF 128
#define HH 128
#define NG 512   // 4*H

__device__ __forceinline__ unsigned short f2bf(float x) {
  union { float f; unsigned u; } v; v.f = x;
  unsigned r = (v.u + 0x7fffu + ((v.u >> 16) & 1u)) >> 16;
  return (unsigned short)r;
}
__device__ __forceinline__ float frcp(float x) { return __builtin_amdgcn_rcpf(x); }
__device__ __forceinline__ float sigf(float x) { return frcp(1.f + __expf(-x)); }
__device__ __forceinline__ float tanh_(float x) {
  float e = __expf(-2.f * x);
  return (1.f - e) * frcp(1.f + e);
}
// XOR swizzle for 256B (128 bf16) rows: spreads 16B chunks across banks
__device__ __forceinline__ unsigned swzb(int row, int kbyte) {
  return (unsigned)(row * 256 + (kbyte ^ ((row & 7) << 4)));
}

// ---------------- K0: prep (w_ih -> bf16, bias = b_ih + b_hh) ----------------
__global__ void k_prep(const float* __restrict__ w_ih, const float* __restrict__ b_ih,
                       const float* __restrict__ b_hh, unsigned short* __restrict__ wihb,
                       float* __restrict__ bias) {
  int g = blockIdx.x * blockDim.x + threadIdx.x;
  int gs = gridDim.x * blockDim.x;
  for (int i = g; i < NG * FF; i += gs) wihb[i] = f2bf(w_ih[i]);
  if (g < NG) bias[g] = b_ih[g] + b_hh[g];
}

// -------- K1: fused a=softmax_f(sum_t x*wx); x_atn = a*x (f32 out) -----------
__global__ __launch_bounds__(256) void k_attn_xatn(const float* __restrict__ x,
                                                   const float* __restrict__ w_lin,
                                                   float* __restrict__ out) {
  __shared__ float sred[256];
  __shared__ float wx[TT];
  __shared__ float aSh[FF];
  __shared__ float red4[4];
  int tid = threadIdx.x;
  int b = blockIdx.x;
  if (tid < TT) wx[tid] = w_lin[2 * HH + tid];
  __syncthreads();
  const float* xb = x + (size_t)b * TT * FF;
  int f = tid & 127, th = tid >> 7;
  float s = 0.f;
#pragma unroll 4
  for (int t = th * 64; t < th * 64 + 64; ++t) s += xb[(size_t)t * FF + f] * wx[t];
  sred[tid] = s;
  __syncthreads();
  float sv = 0.f, e = 0.f;
  if (tid < 128) {
    sv = sred[tid] + sred[tid + 128];
    float m = sv;
#pragma unroll
    for (int d = 1; d < 64; d <<= 1) m = fmaxf(m, __shfl_xor(m, d));
    if ((tid & 63) == 0) red4[tid >> 6] = m;
  }
  __syncthreads();
  if (tid < 128) {
    float m2 = fmaxf(red4[0], red4[1]);
    e = __expf(sv - m2);
    float sum = e;
#pragma unroll
    for (int d = 1; d < 64; d <<= 1) sum += __shfl_xor(sum, d);
    if ((tid & 63) == 0) red4[2 + (tid >> 6)] = sum;
  }
  __syncthreads();
  if (tid < 128) aSh[tid] = e * frcp(red4[2] + red4[3]);
  __syncthreads();
  const float4* xb4 = (const float4*)xb;
  float4* ob4 = (float4*)(out + (size_t)b * TT * FF);
  for (int i4 = tid; i4 < TT * FF / 4; i4 += 256) {
    float4 xv = xb4[i4];
    int f0 = (i4 * 4) & 127;
    float4 av = *(const float4*)(aSh + f0);
    float4 o;
    o.x = xv.x * av.x; o.y = xv.y * av.y;
    o.z = xv.z * av.z; o.w = xv.w * av.w;
    ob4[i4] = o;
  }
}

// -------- K2: full recurrence, K=256 MFMA ([h | xa] @ [w_hh | w_ih]^T) -------
__global__ __launch_bounds__(512, 1) void k_rnn_full(const float* __restrict__ w_hh,
                                                     const unsigned short* __restrict__ wihb,
                                                     const float* __restrict__ bias,
                                                     const float* __restrict__ xa,
                                                     float* __restrict__ enc) {
  __shared__ unsigned char hLds[2][4096];  // 16 rows x 128 bf16 (rows 8..15 zero)
  __shared__ unsigned char xLds[2][4096];
  int tid = threadIdx.x;
  int l = tid & 63, w = tid >> 6;
  int lg = l >> 4;
  int b0 = blockIdx.x * 8;
  int kl = w * 16 + (l & 15);  // this lane's gate column k in [0,128)

  // B-fragments: per gate g, ks 0..3 = w_hh (K=h), ks 4..7 = w_ih (K=xa)
  bf16x8 Bf[4][8];
  float bcg[4];
#pragma unroll
  for (int g = 0; g < 4; ++g) {
    int n = g * 128 + kl;  // column of the 512 gates
    bcg[g] = bias[n];
#pragma unroll
    for (int ks = 0; ks < 4; ++ks) {
      const float* p = w_hh + (size_t)n * HH + ks * 32 + lg * 8;
      float4 v0 = *(const float4*)p;
      float4 v1 = *(const float4*)(p + 4);
      bf16x8 bb;
      bb[0] = (short)f2bf(v0.x); bb[1] = (short)f2bf(v0.y);
      bb[2] = (short)f2bf(v0.z); bb[3] = (short)f2bf(v0.w);
      bb[4] = (short)f2bf(v1.x); bb[5] = (short)f2bf(v1.y);
      bb[6] = (short)f2bf(v1.z); bb[7] = (short)f2bf(v1.w);
      Bf[g][ks] = bb;
      Bf[g][4 + ks] = *(const bf16x8*)(wihb + (size_t)n * FF + ks * 32 + lg * 8);
    }
  }
  // zero both h/x double-buffers (rows 8..15 stay zero forever)
  for (int i = tid; i < 2048; i += 512) {
    ((unsigned*)hLds)[i] = 0u;
    ((unsigned*)xLds)[i] = 0u;
  }
  __syncthreads();
  // stage xa[:, t=0, :]
  int srow = tid >> 6, sf = (tid & 63) * 2;
  const float* xrow = xa + (size_t)(b0 + srow) * TT * FF + sf;
  {
    float2 v = *(const float2*)xrow;
    unsigned pk = (unsigned)f2bf(v.x) | ((unsigned)f2bf(v.y) << 16);
    *(unsigned*)(xLds[0] + swzb(srow, sf * 2)) = pk;
  }
  __syncthreads();

  bool act = (lg < 2);
  int brow = lg * 4;
  float c[4] = {0.f, 0.f, 0.f, 0.f};
  for (int t = 0; t < TT; ++t) {
    int cur = t & 1, nxt = cur ^ 1;
    // prefetch next step's xa row segment
    float2 pv;
    if (t + 1 < TT) pv = *(const float2*)(xrow + (size_t)(t + 1) * FF);
    // A-fragments: h and xa tiles (rows 8..15 zero)
    bf16x8 Ah[4], Ax[4];
#pragma unroll
    for (int ks = 0; ks < 4; ++ks) {
      Ah[ks] = *(const bf16x8*)(hLds[cur] + swzb(l & 15, ks * 64 + lg * 16));
      Ax[ks] = *(const bf16x8*)(xLds[cur] + swzb(l & 15, ks * 64 + lg * 16));
    }
    f32x4 a0 = {0.f,0.f,0.f,0.f}, a1 = {0.f,0.f,0.f,0.f};
    f32x4 a2 = {0.f,0.f,0.f,0.f}, a3 = {0.f,0.f,0.f,0.f};
#pragma unroll
    for (int ks = 0; ks < 4; ++ks) {
      a0 = __builtin_amdgcn_mfma_f32_16x16x32_bf16(Ah[ks], Bf[0][ks], a0, 0, 0, 0);
      a1 = __builtin_amdgcn_mfma_f32_16x16x32_bf16(Ah[ks], Bf[1][ks], a1, 0, 0, 0);
      a2 = __builtin_amdgcn_mfma_f32_16x16x32_bf16(Ah[ks], Bf[2][ks], a2, 0, 0, 0);
      a3 = __builtin_amdgcn_mfma_f32_16x16x32_bf16(Ah[ks], Bf[3][ks], a3, 0, 0, 0);
    }
#pragma unroll
    for (int ks = 0; ks < 4; ++ks) {
      a0 = __builtin_amdgcn_mfma_f32_16x16x32_bf16(Ax[ks], Bf[0][4 + ks], a0, 0, 0, 0);
      a1 = __builtin_amdgcn_mfma_f32_16x16x32_bf16(Ax[ks], Bf[1][4 + ks], a1, 0, 0, 0);
      a2 = __builtin_amdgcn_mfma_f32_16x16x32_bf16(Ax[ks], Bf[2][4 + ks], a2, 0, 0, 0);
      a3 = __builtin_amdgcn_mfma_f32_16x16x32_bf16(Ax[ks], Bf[3][4 + ks], a3, 0, 0, 0);
    }
    if (act) {
#pragma unroll
      for (int r = 0; r < 4; ++r) {
        int bg = b0 + brow + r;
        float gi = a0[r] + bcg[0];
        float gf = a1[r] + bcg[1];
        float gg = a2[r] + bcg[2];
        float go = a3[r] + bcg[3];
        float cn = sigf(gf) * c[r] + sigf(gi) * tanh_(gg);
        c[r] = cn;
        float hv = sigf(go) * tanh_(cn);
        enc[((size_t)bg * TT + t) * HH + kl] = hv;
        *(unsigned short*)(hLds[nxt] + swzb(brow + r, kl * 2)) = f2bf(hv);
      }
    }
    if (t + 1 < TT) {
      unsigned pk = (unsigned)f2bf(pv.x) | ((unsigned)f2bf(pv.y) << 16);
      *(unsigned*)(xLds[nxt] + swzb(srow, sf * 2)) = pk;
    }
    __syncthreads();
  }
}

extern "C" void kernel_launch(void* const* d_in, const int* in_sizes, int n_in,
                              void* d_out, int out_size, void* d_ws, size_t ws_size,
                              hipStream_t stream) {
  (void)in_sizes; (void)n_in; (void)out_size; (void)ws_size;
  const float* x     = (const float*)d_in[0];
  const float* w_lin = (const float*)d_in[1];
  const float* w_ih  = (const float*)d_in[3];
  const float* w_hh  = (const float*)d_in[4];
  const float* b_ih  = (const float*)d_in[5];
  const float* b_hh  = (const float*)d_in[6];
  float* out = (float*)d_out;  // [x_atn (2048*128*128) | x_enc (2048*128*128)] f32

  char* ws = (char*)d_ws;
  float* bias          = (float*)ws;                        // 2 KB
  unsigned short* wihb = (unsigned short*)(ws + 4096);      // 128 KB

  float* enc = out + (size_t)NB * TT * FF;

  k_prep<<<dim3(64), dim3(256), 0, stream>>>(w_ih, b_ih, b_hh, wihb, bias);
  k_attn_xatn<<<dim3(NB), dim3(256), 0, stream>>>(x, w_lin, out);
  k_rnn_full<<<dim3(256), dim3(512), 0, stream>>>(w_hh, wihb, bias, out, enc);
}

// Round 4
// 242.953 us; speedup vs baseline: 2.3279x; 1.0893x over previous
//
#include <hip/hip_runtime.h>
#include <hip/hip_bf16.h>

typedef __attribute__((ext_vector_type(8))) short bf16x8;
typedef __attribute__((ext_vector_type(4))) float f32x4;

#define NB 2048
#define TT 128   // T-1
#define FF 128
#define HH 128
#define NG 512   // 4*H

__device__ __forceinline__ unsigned short f2bf(float x) {
  union { float f; unsigned u; } v; v.f = x;
  unsigned r = (v.u + 0x7fffu + ((v.u >> 16) & 1u)) >> 16;
  return (unsigned short)r;
}
__device__ __forceinline__ float frcp(float x) { return __builtin_amdgcn_rcpf(x); }
__device__ __forceinline__ float sigf(float x) { return frcp(1.f + __expf(-x)); }
__device__ __forceinline__ float tanh_(float x) {
  float e = __expf(-2.f * x);
  return (1.f - e) * frcp(1.f + e);
}
// XOR swizzle for 256B (128 bf16) rows: spreads 16B chunks across banks
__device__ __forceinline__ unsigned swzb(int row, int kbyte) {
  return (unsigned)(row * 256 + (kbyte ^ ((row & 7) << 4)));
}

// ---------------- K0: prep (w_ih -> bf16, bias = b_ih + b_hh) ----------------
__global__ void k_prep(const float* __restrict__ w_ih, const float* __restrict__ b_ih,
                       const float* __restrict__ b_hh, unsigned short* __restrict__ wihb,
                       float* __restrict__ bias) {
  int g = blockIdx.x * blockDim.x + threadIdx.x;
  int gs = gridDim.x * blockDim.x;
  for (int i = g; i < NG * FF; i += gs) wihb[i] = f2bf(w_ih[i]);
  if (g < NG) bias[g] = b_ih[g] + b_hh[g];
}

// -------- K1: fused a=softmax_f(sum_t x*wx); x_atn = a*x (f32 out) -----------
__global__ __launch_bounds__(256) void k_attn_xatn(const float* __restrict__ x,
                                                   const float* __restrict__ w_lin,
                                                   float* __restrict__ out) {
  __shared__ float sred[256];
  __shared__ float wx[TT];
  __shared__ float aSh[FF];
  __shared__ float red4[4];
  int tid = threadIdx.x;
  int b = blockIdx.x;
  if (tid < TT) wx[tid] = w_lin[2 * HH + tid];
  __syncthreads();
  const float* xb = x + (size_t)b * TT * FF;
  int f = tid & 127, th = tid >> 7;
  float s = 0.f;
#pragma unroll 4
  for (int t = th * 64; t < th * 64 + 64; ++t) s += xb[(size_t)t * FF + f] * wx[t];
  sred[tid] = s;
  __syncthreads();
  float sv = 0.f, e = 0.f;
  if (tid < 128) {
    sv = sred[tid] + sred[tid + 128];
    float m = sv;
#pragma unroll
    for (int d = 1; d < 64; d <<= 1) m = fmaxf(m, __shfl_xor(m, d));
    if ((tid & 63) == 0) red4[tid >> 6] = m;
  }
  __syncthreads();
  if (tid < 128) {
    float m2 = fmaxf(red4[0], red4[1]);
    e = __expf(sv - m2);
    float sum = e;
#pragma unroll
    for (int d = 1; d < 64; d <<= 1) sum += __shfl_xor(sum, d);
    if ((tid & 63) == 0) red4[2 + (tid >> 6)] = sum;
  }
  __syncthreads();
  if (tid < 128) aSh[tid] = e * frcp(red4[2] + red4[3]);
  __syncthreads();
  const float4* xb4 = (const float4*)xb;
  float4* ob4 = (float4*)(out + (size_t)b * TT * FF);
  for (int i4 = tid; i4 < TT * FF / 4; i4 += 256) {
    float4 xv = xb4[i4];
    int f0 = (i4 * 4) & 127;
    float4 av = *(const float4*)(aSh + f0);
    float4 o;
    o.x = xv.x * av.x; o.y = xv.y * av.y;
    o.z = xv.z * av.z; o.w = xv.w * av.w;
    ob4[i4] = o;
  }
}

// -------- K2: full recurrence, K=256 MFMA ([h | xa] @ [w_hh | w_ih]^T) -------
// 8 batch rows/block, duplicated into A rows 8..15 so ALL 64 lanes do pointwise.
__global__ __launch_bounds__(512, 1) void k_rnn_full(const float* __restrict__ w_hh,
                                                     const unsigned short* __restrict__ wihb,
                                                     const float* __restrict__ bias,
                                                     const float* __restrict__ xa,
                                                     float* __restrict__ enc) {
  __shared__ unsigned char hLds[2][4096];  // 16 rows x 128 bf16 (rows 8..15 = dup of 0..7)
  __shared__ unsigned char xLds[2][4096];
  int tid = threadIdx.x;
  int l = tid & 63, w = tid >> 6;
  int lg = l >> 4;
  bool low = (lg < 2);
  int b0 = blockIdx.x * 8;
  int kl = w * 16 + (l & 15);  // this lane's gate column k in [0,128)

  // B-fragments: per gate g, ks 0..3 = w_hh (K=h), ks 4..7 = w_ih (K=xa)
  bf16x8 Bf[4][8];
  float bcg[4];
#pragma unroll
  for (int g = 0; g < 4; ++g) {
    int n = g * 128 + kl;  // column of the 512 gates
    bcg[g] = bias[n];
#pragma unroll
    for (int ks = 0; ks < 4; ++ks) {
      const float* p = w_hh + (size_t)n * HH + ks * 32 + lg * 8;
      float4 v0 = *(const float4*)p;
      float4 v1 = *(const float4*)(p + 4);
      bf16x8 bb;
      bb[0] = (short)f2bf(v0.x); bb[1] = (short)f2bf(v0.y);
      bb[2] = (short)f2bf(v0.z); bb[3] = (short)f2bf(v0.w);
      bb[4] = (short)f2bf(v1.x); bb[5] = (short)f2bf(v1.y);
      bb[6] = (short)f2bf(v1.z); bb[7] = (short)f2bf(v1.w);
      Bf[g][ks] = bb;
      Bf[g][4 + ks] = *(const bf16x8*)(wihb + (size_t)n * FF + ks * 32 + lg * 8);
    }
  }
  // pin weight fragments in VGPRs (forbid rematerialization inside the t-loop)
#pragma unroll
  for (int g = 0; g < 4; ++g)
#pragma unroll
    for (int ks = 0; ks < 8; ++ks)
      asm volatile("" : "+v"(Bf[g][ks]));

  // zero both h/x double-buffers
  for (int i = tid; i < 2048; i += 512) {
    ((unsigned*)hLds)[i] = 0u;
    ((unsigned*)xLds)[i] = 0u;
  }
  __syncthreads();
  // stage xa[:, t=0, :] (with row duplication)
  int srow = tid >> 6, sf = (tid & 63) * 2;
  const float* xrow = xa + (size_t)(b0 + srow) * TT * FF + sf;
  {
    float2 v = *(const float2*)xrow;
    unsigned pk = (unsigned)f2bf(v.x) | ((unsigned)f2bf(v.y) << 16);
    *(unsigned*)(xLds[0] + swzb(srow, sf * 2)) = pk;
    *(unsigned*)(xLds[0] + swzb(srow + 8, sf * 2)) = pk;
  }
  __syncthreads();

  int bq0 = ((lg & 1) << 2) | ((lg >> 1) << 1);  // 0,4,2,6 : first batch row this lane owns
  float c0 = 0.f, c1 = 0.f;
  for (int t = 0; t < TT; ++t) {
    int cur = t & 1, nxt = cur ^ 1;
    // prefetch next step's xa row segment
    float2 pv;
    if (t + 1 < TT) pv = *(const float2*)(xrow + (size_t)(t + 1) * FF);
    // A-fragments (rows 8..15 are duplicates)
    bf16x8 Ax[4], Ah[4];
#pragma unroll
    for (int ks = 0; ks < 4; ++ks)
      Ax[ks] = *(const bf16x8*)(xLds[cur] + swzb(l & 15, ks * 64 + lg * 16));
#pragma unroll
    for (int ks = 0; ks < 4; ++ks)
      Ah[ks] = *(const bf16x8*)(hLds[cur] + swzb(l & 15, ks * 64 + lg * 16));
    // 8 independent 4-deep chains: x-side first (hides h ds_read latency)
    f32x4 x0 = {0.f,0.f,0.f,0.f}, x1 = {0.f,0.f,0.f,0.f};
    f32x4 x2 = {0.f,0.f,0.f,0.f}, x3 = {0.f,0.f,0.f,0.f};
    f32x4 h0 = {0.f,0.f,0.f,0.f}, h1 = {0.f,0.f,0.f,0.f};
    f32x4 h2 = {0.f,0.f,0.f,0.f}, h3 = {0.f,0.f,0.f,0.f};
#pragma unroll
    for (int ks = 0; ks < 4; ++ks) {
      x0 = __builtin_amdgcn_mfma_f32_16x16x32_bf16(Ax[ks], Bf[0][4 + ks], x0, 0, 0, 0);
      x1 = __builtin_amdgcn_mfma_f32_16x16x32_bf16(Ax[ks], Bf[1][4 + ks], x1, 0, 0, 0);
      x2 = __builtin_amdgcn_mfma_f32_16x16x32_bf16(Ax[ks], Bf[2][4 + ks], x2, 0, 0, 0);
      x3 = __builtin_amdgcn_mfma_f32_16x16x32_bf16(Ax[ks], Bf[3][4 + ks], x3, 0, 0, 0);
    }
#pragma unroll
    for (int ks = 0; ks < 4; ++ks) {
      h0 = __builtin_amdgcn_mfma_f32_16x16x32_bf16(Ah[ks], Bf[0][ks], h0, 0, 0, 0);
      h1 = __builtin_amdgcn_mfma_f32_16x16x32_bf16(Ah[ks], Bf[1][ks], h1, 0, 0, 0);
      h2 = __builtin_amdgcn_mfma_f32_16x16x32_bf16(Ah[ks], Bf[2][ks], h2, 0, 0, 0);
      h3 = __builtin_amdgcn_mfma_f32_16x16x32_bf16(Ah[ks], Bf[3][ks], h3, 0, 0, 0);
    }
    f32x4 s0 = x0 + h0; s0 += bcg[0];
    f32x4 s1 = x1 + h1; s1 += bcg[1];
    f32x4 s2 = x2 + h2; s2 += bcg[2];
    f32x4 s3 = x3 + h3; s3 += bcg[3];
    // every lane owns 2 (row,col) outputs; constant vector indices only
    float giA = low ? s0[0] : s0[2], giB = low ? s0[1] : s0[3];
    float gfA = low ? s1[0] : s1[2], gfB = low ? s1[1] : s1[3];
    float ggA = low ? s2[0] : s2[2], ggB = low ? s2[1] : s2[3];
    float goA = low ? s3[0] : s3[2], goB = low ? s3[1] : s3[3];
    float cnA = sigf(gfA) * c0 + sigf(giA) * tanh_(ggA);
    float cnB = sigf(gfB) * c1 + sigf(giB) * tanh_(ggB);
    c0 = cnA; c1 = cnB;
    float hvA = sigf(goA) * tanh_(cnA);
    float hvB = sigf(goB) * tanh_(cnB);
    enc[((size_t)(b0 + bq0) * TT + t) * HH + kl] = hvA;
    enc[((size_t)(b0 + bq0 + 1) * TT + t) * HH + kl] = hvB;
    unsigned short ha = f2bf(hvA), hb = f2bf(hvB);
    *(unsigned short*)(hLds[nxt] + swzb(bq0, kl * 2)) = ha;
    *(unsigned short*)(hLds[nxt] + swzb(bq0 + 8, kl * 2)) = ha;
    *(unsigned short*)(hLds[nxt] + swzb(bq0 + 1, kl * 2)) = hb;
    *(unsigned short*)(hLds[nxt] + swzb(bq0 + 9, kl * 2)) = hb;
    if (t + 1 < TT) {
      unsigned pk = (unsigned)f2bf(pv.x) | ((unsigned)f2bf(pv.y) << 16);
      *(unsigned*)(xLds[nxt] + swzb(srow, sf * 2)) = pk;
      *(unsigned*)(xLds[nxt] + swzb(srow + 8, sf * 2)) = pk;
    }
    __syncthreads();
  }
}

extern "C" void kernel_launch(void* const* d_in, const int* in_sizes, int n_in,
                              void* d_out, int out_size, void* d_ws, size_t ws_size,
                              hipStream_t stream) {
  (void)in_sizes; (void)n_in; (void)out_size; (void)ws_size;
  const float* x     = (const float*)d_in[0];
  const float* w_lin = (const float*)d_in[1];
  const float* w_ih  = (const float*)d_in[3];
  const float* w_hh  = (const float*)d_in[4];
  const float* b_ih  = (const float*)d_in[5];
  const float* b_hh  = (const float*)d_in[6];
  float* out = (float*)d_out;  // [x_atn (2048*128*128) | x_enc (2048*128*128)] f32

  char* ws = (char*)d_ws;
  float* bias          = (float*)ws;                        // 2 KB
  unsigned short* wihb = (unsigned short*)(ws + 4096);      // 128 KB

  float* enc = out + (size_t)NB * TT * FF;

  k_prep<<<dim3(64), dim3(256), 0, stream>>>(w_ih, b_ih, b_hh, wihb, bias);
  k_attn_xatn<<<dim3(NB), dim3(256), 0, stream>>>(x, w_lin, out);
  k_rnn_full<<<dim3(256), dim3(512), 0, stream>>>(w_hh, wihb, bias, out, enc);
}

// Round 5
// 222.253 us; speedup vs baseline: 2.5448x; 1.0931x over previous
//
#include <hip/hip_runtime.h>
#include <hip/hip_bf16.h>

typedef __attribute__((ext_vector_type(8))) short bf16x8;
typedef __attribute__((ext_vector_type(4))) float f32x4;

#define NB 2048
#define TT 128   // T-1
#define FF 128
#define HH 128
#define NG 512   // 4*H

__device__ __forceinline__ unsigned short f2bf(float x) {
  union { float f; unsigned u; } v; v.f = x;
  unsigned r = (v.u + 0x7fffu + ((v.u >> 16) & 1u)) >> 16;
  return (unsigned short)r;
}
__device__ __forceinline__ float frcp(float x) { return __builtin_amdgcn_rcpf(x); }
__device__ __forceinline__ float sigf(float x) { return frcp(1.f + __expf(-x)); }
__device__ __forceinline__ float tanh_(float x) {
  float e = __expf(-2.f * x);
  return (1.f - e) * frcp(1.f + e);
}
// XOR swizzle for 256B (128 bf16) rows: spreads 16B chunks across banks
__device__ __forceinline__ unsigned swzb(int row, int kbyte) {
  return (unsigned)(row * 256 + (kbyte ^ ((row & 7) << 4)));
}
// barrier that does NOT drain vmcnt (enc stores are fire-and-forget)
__device__ __forceinline__ void barrier_lds() {
  asm volatile("s_waitcnt lgkmcnt(0)" ::: "memory");
  __builtin_amdgcn_s_barrier();
  __builtin_amdgcn_sched_barrier(0);
}

// ------- K0: prep (w_ih, w_hh -> bf16; bias = b_ih + b_hh) -------------------
__global__ void k_prep(const float* __restrict__ w_ih, const float* __restrict__ w_hh,
                       const float* __restrict__ b_ih, const float* __restrict__ b_hh,
                       unsigned short* __restrict__ wihb, unsigned short* __restrict__ whhb,
                       float* __restrict__ bias) {
  int g = blockIdx.x * blockDim.x + threadIdx.x;
  int gs = gridDim.x * blockDim.x;
  for (int i = g; i < NG * FF; i += gs) {
    wihb[i] = f2bf(w_ih[i]);
    whhb[i] = f2bf(w_hh[i]);
  }
  if (g < NG) bias[g] = b_ih[g] + b_hh[g];
}

// -------- K1: fused a=softmax_f(sum_t x*wx); x_atn = a*x (f32 out) -----------
__global__ __launch_bounds__(256) void k_attn_xatn(const float* __restrict__ x,
                                                   const float* __restrict__ w_lin,
                                                   float* __restrict__ out) {
  __shared__ float sred[256];
  __shared__ float wx[TT];
  __shared__ float aSh[FF];
  __shared__ float red4[4];
  int tid = threadIdx.x;
  int b = blockIdx.x;
  if (tid < TT) wx[tid] = w_lin[2 * HH + tid];
  __syncthreads();
  const float* xb = x + (size_t)b * TT * FF;
  int f = tid & 127, th = tid >> 7;
  float s = 0.f;
#pragma unroll 4
  for (int t = th * 64; t < th * 64 + 64; ++t) s += xb[(size_t)t * FF + f] * wx[t];
  sred[tid] = s;
  __syncthreads();
  float sv = 0.f, e = 0.f;
  if (tid < 128) {
    sv = sred[tid] + sred[tid + 128];
    float m = sv;
#pragma unroll
    for (int d = 1; d < 64; d <<= 1) m = fmaxf(m, __shfl_xor(m, d));
    if ((tid & 63) == 0) red4[tid >> 6] = m;
  }
  __syncthreads();
  if (tid < 128) {
    float m2 = fmaxf(red4[0], red4[1]);
    e = __expf(sv - m2);
    float sum = e;
#pragma unroll
    for (int d = 1; d < 64; d <<= 1) sum += __shfl_xor(sum, d);
    if ((tid & 63) == 0) red4[2 + (tid >> 6)] = sum;
  }
  __syncthreads();
  if (tid < 128) aSh[tid] = e * frcp(red4[2] + red4[3]);
  __syncthreads();
  const float4* xb4 = (const float4*)xb;
  float4* ob4 = (float4*)(out + (size_t)b * TT * FF);
  for (int i4 = tid; i4 < TT * FF / 4; i4 += 256) {
    float4 xv = xb4[i4];
    int f0 = (i4 * 4) & 127;
    float4 av = *(const float4*)(aSh + f0);
    float4 o;
    o.x = xv.x * av.x; o.y = xv.y * av.y;
    o.z = xv.z * av.z; o.w = xv.w * av.w;
    ob4[i4] = o;
  }
}

// -------- K2: full recurrence, K=256 MFMA ([h | xa] @ [w_hh | w_ih]^T) -------
// 8 batch rows/block (dup into rows 8..15), x-GEMM pipelined one step ahead.
__global__ __launch_bounds__(512, 2) void k_rnn_full(const unsigned short* __restrict__ whhb,
                                                     const unsigned short* __restrict__ wihb,
                                                     const float* __restrict__ bias,
                                                     const float* __restrict__ xa,
                                                     float* __restrict__ enc) {
  __shared__ unsigned char hLds[2][4096];  // 16 rows x 128 bf16 (8..15 dup of 0..7)
  __shared__ unsigned char xLds[2][4096];
  int tid = threadIdx.x;
  int l = tid & 63, w = tid >> 6;
  int lg = l >> 4;
  bool low = (lg < 2);
  int b0 = blockIdx.x * 8;
  int kl = w * 16 + (l & 15);  // gate column k in [0,128)

  // B-fragments: per gate g, ks 0..3 = w_hh (K=h), ks 4..7 = w_ih (K=xa)
  bf16x8 Bf[4][8];
  float bcg[4];
#pragma unroll
  for (int g = 0; g < 4; ++g) {
    int n = g * 128 + kl;
    bcg[g] = bias[n];
#pragma unroll
    for (int ks = 0; ks < 4; ++ks) {
      Bf[g][ks]     = *(const bf16x8*)(whhb + (size_t)n * HH + ks * 32 + lg * 8);
      Bf[g][4 + ks] = *(const bf16x8*)(wihb + (size_t)n * FF + ks * 32 + lg * 8);
    }
  }
  // zero both h buffers
  for (int i = tid; i < 2048; i += 512) {
    ((unsigned*)hLds)[i] = 0u;
    ((unsigned*)xLds)[i] = 0u;
  }
  int srow = tid >> 6, sf = (tid & 63) * 2;
  const float* xrow = xa + (size_t)(b0 + srow) * TT * FF + sf;
  // prologue: stage xa(0) -> xLds[0]
  {
    float2 v = *(const float2*)xrow;
    unsigned pk = (unsigned)f2bf(v.x) | ((unsigned)f2bf(v.y) << 16);
    *(unsigned*)(xLds[0] + swzb(srow, sf * 2)) = pk;
    *(unsigned*)(xLds[0] + swzb(srow + 8, sf * 2)) = pk;
  }
  barrier_lds();
  // xaccA = x-gates(0); stage xa(1) -> xLds[1]
  f32x4 xaccA0 = {0,0,0,0}, xaccA1 = {0,0,0,0}, xaccA2 = {0,0,0,0}, xaccA3 = {0,0,0,0};
  f32x4 xaccB0 = {0,0,0,0}, xaccB1 = {0,0,0,0}, xaccB2 = {0,0,0,0}, xaccB3 = {0,0,0,0};
  {
    float2 v = *(const float2*)(xrow + FF);
    bf16x8 Ax[4];
#pragma unroll
    for (int ks = 0; ks < 4; ++ks)
      Ax[ks] = *(const bf16x8*)(xLds[0] + swzb(l & 15, ks * 64 + lg * 16));
#pragma unroll
    for (int ks = 0; ks < 4; ++ks) {
      xaccA0 = __builtin_amdgcn_mfma_f32_16x16x32_bf16(Ax[ks], Bf[0][4 + ks], xaccA0, 0, 0, 0);
      xaccA1 = __builtin_amdgcn_mfma_f32_16x16x32_bf16(Ax[ks], Bf[1][4 + ks], xaccA1, 0, 0, 0);
      xaccA2 = __builtin_amdgcn_mfma_f32_16x16x32_bf16(Ax[ks], Bf[2][4 + ks], xaccA2, 0, 0, 0);
      xaccA3 = __builtin_amdgcn_mfma_f32_16x16x32_bf16(Ax[ks], Bf[3][4 + ks], xaccA3, 0, 0, 0);
    }
    unsigned pk = (unsigned)f2bf(v.x) | ((unsigned)f2bf(v.y) << 16);
    *(unsigned*)(xLds[1] + swzb(srow, sf * 2)) = pk;
    *(unsigned*)(xLds[1] + swzb(srow + 8, sf * 2)) = pk;
  }
  barrier_lds();

  int bq0 = ((lg & 1) << 2) | ((lg >> 1) << 1);  // 0,4,2,6
  float c0 = 0.f, c1 = 0.f;
  float* pA = enc + (size_t)(b0 + bq0) * TT * HH + kl;
  float* pB = enc + (size_t)(b0 + bq0 + 1) * TT * HH + kl;

#define RNN_BODY(tc, CUR, NXT, XU0, XU1, XU2, XU3, XN0, XN1, XN2, XN3)          \
  {                                                                              \
    float2 pv;                                                                   \
    bool havep = (tc) + 2 < TT;                                                  \
    if (havep) pv = *(const float2*)(xrow + (size_t)((tc) + 2) * FF);            \
    bf16x8 Ah[4];                                                                \
    _Pragma("unroll")                                                            \
    for (int ks = 0; ks < 4; ++ks)                                               \
      Ah[ks] = *(const bf16x8*)(hLds[CUR] + swzb(l & 15, ks * 64 + lg * 16));    \
    f32x4 h0 = {0,0,0,0}, h1 = {0,0,0,0}, h2 = {0,0,0,0}, h3 = {0,0,0,0};        \
    _Pragma("unroll")                                                            \
    for (int ks = 0; ks < 4; ++ks) {                                             \
      h0 = __builtin_amdgcn_mfma_f32_16x16x32_bf16(Ah[ks], Bf[0][ks], h0, 0,0,0);\
      h1 = __builtin_amdgcn_mfma_f32_16x16x32_bf16(Ah[ks], Bf[1][ks], h1, 0,0,0);\
      h2 = __builtin_amdgcn_mfma_f32_16x16x32_bf16(Ah[ks], Bf[2][ks], h2, 0,0,0);\
      h3 = __builtin_amdgcn_mfma_f32_16x16x32_bf16(Ah[ks], Bf[3][ks], h3, 0,0,0);\
    }                                                                            \
    bool havex = (tc) + 1 < TT;                                                  \
    XN0 = (f32x4){0,0,0,0}; XN1 = (f32x4){0,0,0,0};                              \
    XN2 = (f32x4){0,0,0,0}; XN3 = (f32x4){0,0,0,0};                              \
    if (havex) {                                                                 \
      bf16x8 Ax[4];                                                              \
      _Pragma("unroll")                                                          \
      for (int ks = 0; ks < 4; ++ks)                                             \
        Ax[ks] = *(const bf16x8*)(xLds[NXT] + swzb(l & 15, ks * 64 + lg * 16));  \
      _Pragma("unroll")                                                          \
      for (int ks = 0; ks < 4; ++ks) {                                           \
        XN0 = __builtin_amdgcn_mfma_f32_16x16x32_bf16(Ax[ks], Bf[0][4+ks], XN0, 0,0,0);\
        XN1 = __builtin_amdgcn_mfma_f32_16x16x32_bf16(Ax[ks], Bf[1][4+ks], XN1, 0,0,0);\
        XN2 = __builtin_amdgcn_mfma_f32_16x16x32_bf16(Ax[ks], Bf[2][4+ks], XN2, 0,0,0);\
        XN3 = __builtin_amdgcn_mfma_f32_16x16x32_bf16(Ax[ks], Bf[3][4+ks], XN3, 0,0,0);\
      }                                                                          \
    }                                                                            \
    f32x4 s0 = h0 + XU0; s0 += bcg[0];                                           \
    f32x4 s1 = h1 + XU1; s1 += bcg[1];                                           \
    f32x4 s2 = h2 + XU2; s2 += bcg[2];                                           \
    f32x4 s3 = h3 + XU3; s3 += bcg[3];                                           \
    float giA = low ? s0[0] : s0[2], giB = low ? s0[1] : s0[3];                  \
    float gfA = low ? s1[0] : s1[2], gfB = low ? s1[1] : s1[3];                  \
    float ggA = low ? s2[0] : s2[2], ggB = low ? s2[1] : s2[3];                  \
    float goA = low ? s3[0] : s3[2], goB = low ? s3[1] : s3[3];                  \
    float cnA = sigf(gfA) * c0 + sigf(giA) * tanh_(ggA);                         \
    float cnB = sigf(gfB) * c1 + sigf(giB) * tanh_(ggB);                         \
    c0 = cnA; c1 = cnB;                                                          \
    float hvA = sigf(goA) * tanh_(cnA);                                          \
    float hvB = sigf(goB) * tanh_(cnB);                                          \
    pA[(size_t)(tc) * HH] = hvA;                                                 \
    pB[(size_t)(tc) * HH] = hvB;                                                 \
    unsigned short ha = f2bf(hvA), hb = f2bf(hvB);                               \
    *(unsigned short*)(hLds[NXT] + swzb(bq0, kl * 2)) = ha;                      \
    *(unsigned short*)(hLds[NXT] + swzb(bq0 + 8, kl * 2)) = ha;                  \
    *(unsigned short*)(hLds[NXT] + swzb(bq0 + 1, kl * 2)) = hb;                  \
    *(unsigned short*)(hLds[NXT] + swzb(bq0 + 9, kl * 2)) = hb;                  \
    if (havep) {                                                                 \
      unsigned pk = (unsigned)f2bf(pv.x) | ((unsigned)f2bf(pv.y) << 16);         \
      *(unsigned*)(xLds[CUR] + swzb(srow, sf * 2)) = pk;                         \
      *(unsigned*)(xLds[CUR] + swzb(srow + 8, sf * 2)) = pk;                     \
    }                                                                            \
    barrier_lds();                                                               \
  }

  for (int t = 0; t < TT; t += 2) {
    // pin weight fragments every iteration: asm nominally writes them, so the
    // compiler cannot re-load/re-derive them from memory -> true residency
#pragma unroll
    for (int g = 0; g < 4; ++g)
#pragma unroll
      for (int ks = 0; ks < 8; ++ks)
        asm volatile("" : "+v"(Bf[g][ks]));
    RNN_BODY(t,     0, 1, xaccA0, xaccA1, xaccA2, xaccA3, xaccB0, xaccB1, xaccB2, xaccB3)
    RNN_BODY(t + 1, 1, 0, xaccB0, xaccB1, xaccB2, xaccB3, xaccA0, xaccA1, xaccA2, xaccA3)
  }
#undef RNN_BODY
}

extern "C" void kernel_launch(void* const* d_in, const int* in_sizes, int n_in,
                              void* d_out, int out_size, void* d_ws, size_t ws_size,
                              hipStream_t stream) {
  (void)in_sizes; (void)n_in; (void)out_size; (void)ws_size;
  const float* x     = (const float*)d_in[0];
  const float* w_lin = (const float*)d_in[1];
  const float* w_ih  = (const float*)d_in[3];
  const float* w_hh  = (const float*)d_in[4];
  const float* b_ih  = (const float*)d_in[5];
  const float* b_hh  = (const float*)d_in[6];
  float* out = (float*)d_out;  // [x_atn | x_enc] f32

  char* ws = (char*)d_ws;
  float* bias          = (float*)ws;                                 // 2 KB
  unsigned short* wihb = (unsigned short*)(ws + 4096);               // 128 KB
  unsigned short* whhb = (unsigned short*)(ws + 4096 + (1 << 17));   // 128 KB

  float* enc = out + (size_t)NB * TT * FF;

  k_prep<<<dim3(64), dim3(256), 0, stream>>>(w_ih, w_hh, b_ih, b_hh, wihb, whhb, bias);
  k_attn_xatn<<<dim3(NB), dim3(256), 0, stream>>>(x, w_lin, out);
  k_rnn_full<<<dim3(256), dim3(512), 0, stream>>>(whhb, wihb, bias, out, enc);
}

// Round 6
// 220.088 us; speedup vs baseline: 2.5698x; 1.0098x over previous
//
#include <hip/hip_runtime.h>
#include <hip/hip_bf16.h>

typedef __attribute__((ext_vector_type(8))) short bf16x8;
typedef __attribute__((ext_vector_type(4))) float f32x4;

#define NB 2048
#define TT 128   // T-1
#define FF 128
#define HH 128
#define NG 512   // 4*H

__device__ __forceinline__ unsigned short f2bf(float x) {
  union { float f; unsigned u; } v; v.f = x;
  unsigned r = (v.u + 0x7fffu + ((v.u >> 16) & 1u)) >> 16;
  return (unsigned short)r;
}
__device__ __forceinline__ float frcp(float x) { return __builtin_amdgcn_rcpf(x); }
__device__ __forceinline__ float sigf(float x) { return frcp(1.f + __expf(-x)); }
__device__ __forceinline__ float tanh_(float x) {
  float e = __expf(-2.f * x);
  return (1.f - e) * frcp(1.f + e);
}
// XOR swizzle for 256B (128 bf16) rows: spreads 16B chunks across banks
__device__ __forceinline__ unsigned swzb(int row, int kbyte) {
  return (unsigned)(row * 256 + (kbyte ^ ((row & 7) << 4)));
}
// barrier that does NOT drain vmcnt (enc stores are fire-and-forget)
__device__ __forceinline__ void barrier_lds() {
  asm volatile("s_waitcnt lgkmcnt(0)" ::: "memory");
  __builtin_amdgcn_s_barrier();
  __builtin_amdgcn_sched_barrier(0);
}

// ------- K0: prep (w_ih, w_hh -> bf16; bias = b_ih + b_hh) -------------------
__global__ void k_prep(const float* __restrict__ w_ih, const float* __restrict__ w_hh,
                       const float* __restrict__ b_ih, const float* __restrict__ b_hh,
                       unsigned short* __restrict__ wihb, unsigned short* __restrict__ whhb,
                       float* __restrict__ bias) {
  int g = blockIdx.x * blockDim.x + threadIdx.x;
  int gs = gridDim.x * blockDim.x;
  for (int i = g; i < NG * FF; i += gs) {
    wihb[i] = f2bf(w_ih[i]);
    whhb[i] = f2bf(w_hh[i]);
  }
  if (g < NG) bias[g] = b_ih[g] + b_hh[g];
}

// -------- K1: fused a=softmax_f(sum_t x*wx); x_atn = a*x (f32 out) -----------
__global__ __launch_bounds__(256) void k_attn_xatn(const float* __restrict__ x,
                                                   const float* __restrict__ w_lin,
                                                   float* __restrict__ out) {
  __shared__ float sred[256];
  __shared__ float wx[TT];
  __shared__ float aSh[FF];
  __shared__ float red4[4];
  int tid = threadIdx.x;
  int b = blockIdx.x;
  if (tid < TT) wx[tid] = w_lin[2 * HH + tid];
  __syncthreads();
  const float* xb = x + (size_t)b * TT * FF;
  int f = tid & 127, th = tid >> 7;
  float s = 0.f;
#pragma unroll 4
  for (int t = th * 64; t < th * 64 + 64; ++t) s += xb[(size_t)t * FF + f] * wx[t];
  sred[tid] = s;
  __syncthreads();
  float sv = 0.f, e = 0.f;
  if (tid < 128) {
    sv = sred[tid] + sred[tid + 128];
    float m = sv;
#pragma unroll
    for (int d = 1; d < 64; d <<= 1) m = fmaxf(m, __shfl_xor(m, d));
    if ((tid & 63) == 0) red4[tid >> 6] = m;
  }
  __syncthreads();
  if (tid < 128) {
    float m2 = fmaxf(red4[0], red4[1]);
    e = __expf(sv - m2);
    float sum = e;
#pragma unroll
    for (int d = 1; d < 64; d <<= 1) sum += __shfl_xor(sum, d);
    if ((tid & 63) == 0) red4[2 + (tid >> 6)] = sum;
  }
  __syncthreads();
  if (tid < 128) aSh[tid] = e * frcp(red4[2] + red4[3]);
  __syncthreads();
  const float4* xb4 = (const float4*)xb;
  float4* ob4 = (float4*)(out + (size_t)b * TT * FF);
  for (int i4 = tid; i4 < TT * FF / 4; i4 += 256) {
    float4 xv = xb4[i4];
    int f0 = (i4 * 4) & 127;
    float4 av = *(const float4*)(aSh + f0);
    float4 o;
    o.x = xv.x * av.x; o.y = xv.y * av.y;
    o.z = xv.z * av.z; o.w = xv.w * av.w;
    ob4[i4] = o;
  }
}

// -------- K2: full recurrence, K=256 MFMA ([h | xa] @ [w_hh | w_ih]^T) -------
// 8 batch rows/block (dup into rows 8..15), x-GEMM pipelined one step ahead.
// Bias is folded into the x-accumulator init (C-in of the x-GEMM).
__global__ __launch_bounds__(512, 1) void k_rnn_full(const unsigned short* __restrict__ whhb,
                                                     const unsigned short* __restrict__ wihb,
                                                     const float* __restrict__ bias,
                                                     const float* __restrict__ xa,
                                                     float* __restrict__ enc) {
  __shared__ unsigned char hLds[2][4096];  // 16 rows x 128 bf16 (8..15 dup of 0..7)
  __shared__ unsigned char xLds[2][4096];
  int tid = threadIdx.x;
  int l = tid & 63, w = tid >> 6;
  int lg = l >> 4;
  bool low = (lg < 2);
  int b0 = blockIdx.x * 8;
  int kl = w * 16 + (l & 15);  // gate column k in [0,128)

  // B-fragments: per gate g, ks 0..3 = w_hh (K=h), ks 4..7 = w_ih (K=xa)
  bf16x8 Bf[4][8];
  float bcg[4];
#pragma unroll
  for (int g = 0; g < 4; ++g) {
    int n = g * 128 + kl;
    bcg[g] = bias[n];
#pragma unroll
    for (int ks = 0; ks < 4; ++ks) {
      Bf[g][ks]     = *(const bf16x8*)(whhb + (size_t)n * HH + ks * 32 + lg * 8);
      Bf[g][4 + ks] = *(const bf16x8*)(wihb + (size_t)n * FF + ks * 32 + lg * 8);
    }
  }
  // zero both h buffers
  for (int i = tid; i < 2048; i += 512) {
    ((unsigned*)hLds)[i] = 0u;
    ((unsigned*)xLds)[i] = 0u;
  }
  int srow = tid >> 6, sf = (tid & 63) * 2;
  const float* xrow = xa + (size_t)(b0 + srow) * TT * FF + sf;
  // prologue: stage xa(0) -> xLds[0]
  {
    float2 v = *(const float2*)xrow;
    unsigned pk = (unsigned)f2bf(v.x) | ((unsigned)f2bf(v.y) << 16);
    *(unsigned*)(xLds[0] + swzb(srow, sf * 2)) = pk;
    *(unsigned*)(xLds[0] + swzb(srow + 8, sf * 2)) = pk;
  }
  barrier_lds();
  // xaccA = bias + x-gates(0); stage xa(1) -> xLds[1]
  f32x4 xaccA0 = {bcg[0],bcg[0],bcg[0],bcg[0]}, xaccA1 = {bcg[1],bcg[1],bcg[1],bcg[1]};
  f32x4 xaccA2 = {bcg[2],bcg[2],bcg[2],bcg[2]}, xaccA3 = {bcg[3],bcg[3],bcg[3],bcg[3]};
  f32x4 xaccB0, xaccB1, xaccB2, xaccB3;
  {
    float2 v = *(const float2*)(xrow + FF);
    bf16x8 Ax[4];
#pragma unroll
    for (int ks = 0; ks < 4; ++ks)
      Ax[ks] = *(const bf16x8*)(xLds[0] + swzb(l & 15, ks * 64 + lg * 16));
#pragma unroll
    for (int ks = 0; ks < 4; ++ks) {
      xaccA0 = __builtin_amdgcn_mfma_f32_16x16x32_bf16(Ax[ks], Bf[0][4 + ks], xaccA0, 0, 0, 0);
      xaccA1 = __builtin_amdgcn_mfma_f32_16x16x32_bf16(Ax[ks], Bf[1][4 + ks], xaccA1, 0, 0, 0);
      xaccA2 = __builtin_amdgcn_mfma_f32_16x16x32_bf16(Ax[ks], Bf[2][4 + ks], xaccA2, 0, 0, 0);
      xaccA3 = __builtin_amdgcn_mfma_f32_16x16x32_bf16(Ax[ks], Bf[3][4 + ks], xaccA3, 0, 0, 0);
    }
    unsigned pk = (unsigned)f2bf(v.x) | ((unsigned)f2bf(v.y) << 16);
    *(unsigned*)(xLds[1] + swzb(srow, sf * 2)) = pk;
    *(unsigned*)(xLds[1] + swzb(srow + 8, sf * 2)) = pk;
  }
  barrier_lds();

  int bq0 = ((lg & 1) << 2) | ((lg >> 1) << 1);  // 0,4,2,6
  float c0 = 0.f, c1 = 0.f;
  float* pA = enc + (size_t)(b0 + bq0) * TT * HH + kl;
  float* pB = enc + (size_t)(b0 + bq0 + 1) * TT * HH + kl;

#define RNN_BODY(tc, CUR, NXT, XU0, XU1, XU2, XU3, XN0, XN1, XN2, XN3)          \
  {                                                                              \
    float2 pv;                                                                   \
    bool havep = (tc) + 2 < TT;                                                  \
    if (havep) pv = *(const float2*)(xrow + (size_t)((tc) + 2) * FF);            \
    bf16x8 Ah[4];                                                                \
    _Pragma("unroll")                                                            \
    for (int ks = 0; ks < 4; ++ks)                                               \
      Ah[ks] = *(const bf16x8*)(hLds[CUR] + swzb(l & 15, ks * 64 + lg * 16));    \
    f32x4 h0 = {0,0,0,0}, h1 = {0,0,0,0}, h2 = {0,0,0,0}, h3 = {0,0,0,0};        \
    _Pragma("unroll")                                                            \
    for (int ks = 0; ks < 4; ++ks) {                                             \
      h0 = __builtin_amdgcn_mfma_f32_16x16x32_bf16(Ah[ks], Bf[0][ks], h0, 0,0,0);\
      h1 = __builtin_amdgcn_mfma_f32_16x16x32_bf16(Ah[ks], Bf[1][ks], h1, 0,0,0);\
      h2 = __builtin_amdgcn_mfma_f32_16x16x32_bf16(Ah[ks], Bf[2][ks], h2, 0,0,0);\
      h3 = __builtin_amdgcn_mfma_f32_16x16x32_bf16(Ah[ks], Bf[3][ks], h3, 0,0,0);\
    }                                                                            \
    bool havex = (tc) + 1 < TT;                                                  \
    XN0 = (f32x4){bcg[0],bcg[0],bcg[0],bcg[0]};                                  \
    XN1 = (f32x4){bcg[1],bcg[1],bcg[1],bcg[1]};                                  \
    XN2 = (f32x4){bcg[2],bcg[2],bcg[2],bcg[2]};                                  \
    XN3 = (f32x4){bcg[3],bcg[3],bcg[3],bcg[3]};                                  \
    if (havex) {                                                                 \
      bf16x8 Ax[4];                                                              \
      _Pragma("unroll")                                                          \
      for (int ks = 0; ks < 4; ++ks)                                             \
        Ax[ks] = *(const bf16x8*)(xLds[NXT] + swzb(l & 15, ks * 64 + lg * 16));  \
      _Pragma("unroll")                                                          \
      for (int ks = 0; ks < 4; ++ks) {                                           \
        XN0 = __builtin_amdgcn_mfma_f32_16x16x32_bf16(Ax[ks], Bf[0][4+ks], XN0, 0,0,0);\
        XN1 = __builtin_amdgcn_mfma_f32_16x16x32_bf16(Ax[ks], Bf[1][4+ks], XN1, 0,0,0);\
        XN2 = __builtin_amdgcn_mfma_f32_16x16x32_bf16(Ax[ks], Bf[2][4+ks], XN2, 0,0,0);\
        XN3 = __builtin_amdgcn_mfma_f32_16x16x32_bf16(Ax[ks], Bf[3][4+ks], XN3, 0,0,0);\
      }                                                                          \
    }                                                                            \
    f32x4 s0 = h0 + XU0;                                                         \
    f32x4 s1 = h1 + XU1;                                                         \
    f32x4 s2 = h2 + XU2;                                                         \
    f32x4 s3 = h3 + XU3;                                                         \
    float giA = low ? s0[0] : s0[2], giB = low ? s0[1] : s0[3];                  \
    float gfA = low ? s1[0] : s1[2], gfB = low ? s1[1] : s1[3];                  \
    float ggA = low ? s2[0] : s2[2], ggB = low ? s2[1] : s2[3];                  \
    float goA = low ? s3[0] : s3[2], goB = low ? s3[1] : s3[3];                  \
    float cnA = sigf(gfA) * c0 + sigf(giA) * tanh_(ggA);                         \
    float cnB = sigf(gfB) * c1 + sigf(giB) * tanh_(ggB);                         \
    c0 = cnA; c1 = cnB;                                                          \
    float hvA = sigf(goA) * tanh_(cnA);                                          \
    float hvB = sigf(goB) * tanh_(cnB);                                          \
    unsigned short ha = f2bf(hvA), hb = f2bf(hvB);                               \
    *(unsigned short*)(hLds[NXT] + swzb(bq0, kl * 2)) = ha;                      \
    *(unsigned short*)(hLds[NXT] + swzb(bq0 + 8, kl * 2)) = ha;                  \
    *(unsigned short*)(hLds[NXT] + swzb(bq0 + 1, kl * 2)) = hb;                  \
    *(unsigned short*)(hLds[NXT] + swzb(bq0 + 9, kl * 2)) = hb;                  \
    pA[(size_t)(tc) * HH] = hvA;                                                 \
    pB[(size_t)(tc) * HH] = hvB;                                                 \
    if (havep) {                                                                 \
      unsigned pk = (unsigned)f2bf(pv.x) | ((unsigned)f2bf(pv.y) << 16);         \
      *(unsigned*)(xLds[CUR] + swzb(srow, sf * 2)) = pk;                         \
      *(unsigned*)(xLds[CUR] + swzb(srow + 8, sf * 2)) = pk;                     \
    }                                                                            \
    barrier_lds();                                                               \
  }

  for (int t = 0; t < TT; t += 2) {
    RNN_BODY(t,     0, 1, xaccA0, xaccA1, xaccA2, xaccA3, xaccB0, xaccB1, xaccB2, xaccB3)
    RNN_BODY(t + 1, 1, 0, xaccB0, xaccB1, xaccB2, xaccB3, xaccA0, xaccA1, xaccA2, xaccA3)
  }
#undef RNN_BODY
}

extern "C" void kernel_launch(void* const* d_in, const int* in_sizes, int n_in,
                              void* d_out, int out_size, void* d_ws, size_t ws_size,
                              hipStream_t stream) {
  (void)in_sizes; (void)n_in; (void)out_size; (void)ws_size;
  const float* x     = (const float*)d_in[0];
  const float* w_lin = (const float*)d_in[1];
  const float* w_ih  = (const float*)d_in[3];
  const float* w_hh  = (const float*)d_in[4];
  const float* b_ih  = (const float*)d_in[5];
  const float* b_hh  = (const float*)d_in[6];
  float* out = (float*)d_out;  // [x_atn | x_enc] f32

  char* ws = (char*)d_ws;
  float* bias          = (float*)ws;                                 // 2 KB
  unsigned short* wihb = (unsigned short*)(ws + 4096);               // 128 KB
  unsigned short* whhb = (unsigned short*)(ws + 4096 + (1 << 17));   // 128 KB

  float* enc = out + (size_t)NB * TT * FF;

  k_prep<<<dim3(64), dim3(256), 0, stream>>>(w_ih, w_hh, b_ih, b_hh, wihb, whhb, bias);
  k_attn_xatn<<<dim3(NB), dim3(256), 0, stream>>>(x, w_lin, out);
  k_rnn_full<<<dim3(256), dim3(512), 0, stream>>>(whhb, wihb, bias, out, enc);
}

// Round 7
// 209.141 us; speedup vs baseline: 2.7043x; 1.0523x over previous
//
#include <hip/hip_runtime.h>
#include <hip/hip_bf16.h>

typedef __attribute__((ext_vector_type(8))) short bf16x8;
typedef __attribute__((ext_vector_type(4))) float f32x4;

#define NB 2048
#define TT 128   // T-1
#define FF 128
#define HH 128
#define NG 512   // 4*H

__device__ __forceinline__ unsigned short f2bf(float x) {
  union { float f; unsigned u; } v; v.f = x;
  unsigned r = (v.u + 0x7fffu + ((v.u >> 16) & 1u)) >> 16;
  return (unsigned short)r;
}
__device__ __forceinline__ unsigned cvtpk_bf16(float lo, float hi) {
  unsigned r;
  asm("v_cvt_pk_bf16_f32 %0, %1, %2" : "=v"(r) : "v"(lo), "v"(hi));
  return r;
}
__device__ __forceinline__ float frcp(float x) { return __builtin_amdgcn_rcpf(x); }
__device__ __forceinline__ float sigf(float x) { return frcp(1.f + __expf(-x)); }
__device__ __forceinline__ float tanh_(float x) {
  float e = __expf(-2.f * x);
  return (1.f - e) * frcp(1.f + e);
}
// XOR swizzle for 256B (128 bf16) rows: spreads 16B chunks across banks
__device__ __forceinline__ unsigned swzb(int row, int kbyte) {
  return (unsigned)(row * 256 + (kbyte ^ ((row & 7) << 4)));
}
// barrier that does NOT drain vmcnt (enc stores are fire-and-forget)
__device__ __forceinline__ void barrier_lds() {
  asm volatile("s_waitcnt lgkmcnt(0)" ::: "memory");
  __builtin_amdgcn_s_barrier();
  __builtin_amdgcn_sched_barrier(0);
}

// ------- K0: prep (w_ih, w_hh -> bf16; bias = b_ih + b_hh) -------------------
__global__ void k_prep(const float* __restrict__ w_ih, const float* __restrict__ w_hh,
                       const float* __restrict__ b_ih, const float* __restrict__ b_hh,
                       unsigned short* __restrict__ wihb, unsigned short* __restrict__ whhb,
                       float* __restrict__ bias) {
  int g = blockIdx.x * blockDim.x + threadIdx.x;
  int gs = gridDim.x * blockDim.x;
  for (int i = g; i < NG * FF; i += gs) {
    wihb[i] = f2bf(w_ih[i]);
    whhb[i] = f2bf(w_hh[i]);
  }
  if (g < NG) bias[g] = b_ih[g] + b_hh[g];
}

// -------- K1: fused a=softmax_f(sum_t x*wx); x_atn = a*x (f32 out) -----------
__global__ __launch_bounds__(256) void k_attn_xatn(const float* __restrict__ x,
                                                   const float* __restrict__ w_lin,
                                                   float* __restrict__ out) {
  __shared__ float sred[256];
  __shared__ float wx[TT];
  __shared__ float aSh[FF];
  __shared__ float red4[4];
  int tid = threadIdx.x;
  int b = blockIdx.x;
  if (tid < TT) wx[tid] = w_lin[2 * HH + tid];
  __syncthreads();
  const float* xb = x + (size_t)b * TT * FF;
  int f = tid & 127, th = tid >> 7;
  float s = 0.f;
#pragma unroll 4
  for (int t = th * 64; t < th * 64 + 64; ++t) s += xb[(size_t)t * FF + f] * wx[t];
  sred[tid] = s;
  __syncthreads();
  float sv = 0.f, e = 0.f;
  if (tid < 128) {
    sv = sred[tid] + sred[tid + 128];
    float m = sv;
#pragma unroll
    for (int d = 1; d < 64; d <<= 1) m = fmaxf(m, __shfl_xor(m, d));
    if ((tid & 63) == 0) red4[tid >> 6] = m;
  }
  __syncthreads();
  if (tid < 128) {
    float m2 = fmaxf(red4[0], red4[1]);
    e = __expf(sv - m2);
    float sum = e;
#pragma unroll
    for (int d = 1; d < 64; d <<= 1) sum += __shfl_xor(sum, d);
    if ((tid & 63) == 0) red4[2 + (tid >> 6)] = sum;
  }
  __syncthreads();
  if (tid < 128) aSh[tid] = e * frcp(red4[2] + red4[3]);
  __syncthreads();
  const float4* xb4 = (const float4*)xb;
  float4* ob4 = (float4*)(out + (size_t)b * TT * FF);
  for (int i4 = tid; i4 < TT * FF / 4; i4 += 256) {
    float4 xv = xb4[i4];
    int f0 = (i4 * 4) & 127;
    float4 av = *(const float4*)(aSh + f0);
    float4 o;
    o.x = xv.x * av.x; o.y = xv.y * av.y;
    o.z = xv.z * av.z; o.w = xv.w * av.w;
    ob4[i4] = o;
  }
}

// -------- K2: full recurrence, K=256 MFMA ([h | xa] @ [w_hh | w_ih]^T) -------
// 8 batch rows/block (dup into rows 8..15), x-GEMM pipelined one step ahead.
// Gate sums exit the matrix pipe directly: h-chain C-in = x-acc (prev step),
// x-chain C-in = persistent bias vectors.
__global__ __launch_bounds__(512, 1) void k_rnn_full(const unsigned short* __restrict__ whhb,
                                                     const unsigned short* __restrict__ wihb,
                                                     const float* __restrict__ bias,
                                                     const float* __restrict__ xa,
                                                     float* __restrict__ enc) {
  __shared__ unsigned char hLds[2][4096];  // 16 rows x 128 bf16 (8..15 dup of 0..7)
  __shared__ unsigned char xLds[2][4096];
  int tid = threadIdx.x;
  int l = tid & 63, w = tid >> 6;
  int lg = l >> 4;
  bool low = (lg < 2);
  int b0 = blockIdx.x * 8;
  int kl = w * 16 + (l & 15);  // gate column k in [0,128)

  // B-fragments: per gate g, ks 0..3 = w_hh (K=h), ks 4..7 = w_ih (K=xa)
  bf16x8 Bf[4][8];
  f32x4 bv0, bv1, bv2, bv3;
  {
    float bc0 = bias[0 * 128 + kl], bc1 = bias[1 * 128 + kl];
    float bc2 = bias[2 * 128 + kl], bc3 = bias[3 * 128 + kl];
    bv0 = (f32x4){bc0, bc0, bc0, bc0};
    bv1 = (f32x4){bc1, bc1, bc1, bc1};
    bv2 = (f32x4){bc2, bc2, bc2, bc2};
    bv3 = (f32x4){bc3, bc3, bc3, bc3};
  }
#pragma unroll
  for (int g = 0; g < 4; ++g) {
    int n = g * 128 + kl;
#pragma unroll
    for (int ks = 0; ks < 4; ++ks) {
      Bf[g][ks]     = *(const bf16x8*)(whhb + (size_t)n * HH + ks * 32 + lg * 8);
      Bf[g][4 + ks] = *(const bf16x8*)(wihb + (size_t)n * FF + ks * 32 + lg * 8);
    }
  }
  // zero both h buffers
  for (int i = tid; i < 2048; i += 512) {
    ((unsigned*)hLds)[i] = 0u;
    ((unsigned*)xLds)[i] = 0u;
  }
  int srow = tid >> 6, sf = (tid & 63) * 2;
  const float* xrow = xa + (size_t)(b0 + srow) * TT * FF + sf;
  // prologue: stage xa(0) -> xLds[0]
  {
    float2 v = *(const float2*)xrow;
    unsigned pk = cvtpk_bf16(v.x, v.y);
    *(unsigned*)(xLds[0] + swzb(srow, sf * 2)) = pk;
    *(unsigned*)(xLds[0] + swzb(srow + 8, sf * 2)) = pk;
  }
  barrier_lds();
  // xaccA = bias + x-gates(0); stage xa(1) -> xLds[1]
  f32x4 xaccA0, xaccA1, xaccA2, xaccA3;
  f32x4 xaccB0, xaccB1, xaccB2, xaccB3;
  {
    float2 v = *(const float2*)(xrow + FF);
    bf16x8 Ax[4];
#pragma unroll
    for (int ks = 0; ks < 4; ++ks)
      Ax[ks] = *(const bf16x8*)(xLds[0] + swzb(l & 15, ks * 64 + lg * 16));
    xaccA0 = bv0; xaccA1 = bv1; xaccA2 = bv2; xaccA3 = bv3;
#pragma unroll
    for (int ks = 0; ks < 4; ++ks) {
      xaccA0 = __builtin_amdgcn_mfma_f32_16x16x32_bf16(Ax[ks], Bf[0][4 + ks], xaccA0, 0, 0, 0);
      xaccA1 = __builtin_amdgcn_mfma_f32_16x16x32_bf16(Ax[ks], Bf[1][4 + ks], xaccA1, 0, 0, 0);
      xaccA2 = __builtin_amdgcn_mfma_f32_16x16x32_bf16(Ax[ks], Bf[2][4 + ks], xaccA2, 0, 0, 0);
      xaccA3 = __builtin_amdgcn_mfma_f32_16x16x32_bf16(Ax[ks], Bf[3][4 + ks], xaccA3, 0, 0, 0);
    }
    unsigned pk = cvtpk_bf16(v.x, v.y);
    *(unsigned*)(xLds[1] + swzb(srow, sf * 2)) = pk;
    *(unsigned*)(xLds[1] + swzb(srow + 8, sf * 2)) = pk;
  }
  barrier_lds();

  int bq0 = ((lg & 1) << 2) | ((lg >> 1) << 1);  // 0,4,2,6
  float c0 = 0.f, c1 = 0.f;
  float* pA = enc + (size_t)(b0 + bq0) * TT * HH + kl;
  float* pB = enc + (size_t)(b0 + bq0 + 1) * TT * HH + kl;

#define RNN_BODY(tc, CUR, NXT, XU0, XU1, XU2, XU3, XN0, XN1, XN2, XN3)          \
  {                                                                              \
    float2 pv;                                                                   \
    bool havep = (tc) + 2 < TT;                                                  \
    if (havep) pv = *(const float2*)(xrow + (size_t)((tc) + 2) * FF);            \
    bf16x8 Ah[4];                                                                \
    _Pragma("unroll")                                                            \
    for (int ks = 0; ks < 4; ++ks)                                               \
      Ah[ks] = *(const bf16x8*)(hLds[CUR] + swzb(l & 15, ks * 64 + lg * 16));    \
    /* gate sums: h-chain accumulates onto (bias + x-gates) from prev step */    \
    f32x4 s0 = XU0, s1 = XU1, s2 = XU2, s3 = XU3;                                \
    _Pragma("unroll")                                                            \
    for (int ks = 0; ks < 4; ++ks) {                                             \
      s0 = __builtin_amdgcn_mfma_f32_16x16x32_bf16(Ah[ks], Bf[0][ks], s0, 0,0,0);\
      s1 = __builtin_amdgcn_mfma_f32_16x16x32_bf16(Ah[ks], Bf[1][ks], s1, 0,0,0);\
      s2 = __builtin_amdgcn_mfma_f32_16x16x32_bf16(Ah[ks], Bf[2][ks], s2, 0,0,0);\
      s3 = __builtin_amdgcn_mfma_f32_16x16x32_bf16(Ah[ks], Bf[3][ks], s3, 0,0,0);\
    }                                                                            \
    bool havex = (tc) + 1 < TT;                                                  \
    if (havex) {                                                                 \
      bf16x8 Ax[4];                                                              \
      _Pragma("unroll")                                                          \
      for (int ks = 0; ks < 4; ++ks)                                             \
        Ax[ks] = *(const bf16x8*)(xLds[NXT] + swzb(l & 15, ks * 64 + lg * 16));  \
      XN0 = bv0; XN1 = bv1; XN2 = bv2; XN3 = bv3;                                \
      _Pragma("unroll")                                                          \
      for (int ks = 0; ks < 4; ++ks) {                                           \
        XN0 = __builtin_amdgcn_mfma_f32_16x16x32_bf16(Ax[ks], Bf[0][4+ks], XN0, 0,0,0);\
        XN1 = __builtin_amdgcn_mfma_f32_16x16x32_bf16(Ax[ks], Bf[1][4+ks], XN1, 0,0,0);\
        XN2 = __builtin_amdgcn_mfma_f32_16x16x32_bf16(Ax[ks], Bf[2][4+ks], XN2, 0,0,0);\
        XN3 = __builtin_amdgcn_mfma_f32_16x16x32_bf16(Ax[ks], Bf[3][4+ks], XN3, 0,0,0);\
      }                                                                          \
    }                                                                            \
    float giA = low ? s0[0] : s0[2], giB = low ? s0[1] : s0[3];                  \
    float gfA = low ? s1[0] : s1[2], gfB = low ? s1[1] : s1[3];                  \
    float ggA = low ? s2[0] : s2[2], ggB = low ? s2[1] : s2[3];                  \
    float goA = low ? s3[0] : s3[2], goB = low ? s3[1] : s3[3];                  \
    float cnA = sigf(gfA) * c0 + sigf(giA) * tanh_(ggA);                         \
    float cnB = sigf(gfB) * c1 + sigf(giB) * tanh_(ggB);                         \
    c0 = cnA; c1 = cnB;                                                          \
    float hvA = sigf(goA) * tanh_(cnA);                                          \
    float hvB = sigf(goB) * tanh_(cnB);                                          \
    unsigned hp = cvtpk_bf16(hvA, hvB);                                          \
    unsigned hq = hp >> 16;                                                      \
    *(unsigned short*)(hLds[NXT] + swzb(bq0, kl * 2)) = (unsigned short)hp;      \
    *(unsigned short*)(hLds[NXT] + swzb(bq0 + 8, kl * 2)) = (unsigned short)hp;  \
    *(unsigned short*)(hLds[NXT] + swzb(bq0 + 1, kl * 2)) = (unsigned short)hq;  \
    *(unsigned short*)(hLds[NXT] + swzb(bq0 + 9, kl * 2)) = (unsigned short)hq;  \
    pA[(size_t)(tc) * HH] = hvA;                                                 \
    pB[(size_t)(tc) * HH] = hvB;                                                 \
    if (havep) {                                                                 \
      unsigned pk = cvtpk_bf16(pv.x, pv.y);                                      \
      *(unsigned*)(xLds[CUR] + swzb(srow, sf * 2)) = pk;                         \
      *(unsigned*)(xLds[CUR] + swzb(srow + 8, sf * 2)) = pk;                     \
    }                                                                            \
    barrier_lds();                                                               \
  }

  for (int t = 0; t < TT; t += 2) {
    RNN_BODY(t,     0, 1, xaccA0, xaccA1, xaccA2, xaccA3, xaccB0, xaccB1, xaccB2, xaccB3)
    RNN_BODY(t + 1, 1, 0, xaccB0, xaccB1, xaccB2, xaccB3, xaccA0, xaccA1, xaccA2, xaccA3)
  }
#undef RNN_BODY
}

extern "C" void kernel_launch(void* const* d_in, const int* in_sizes, int n_in,
                              void* d_out, int out_size, void* d_ws, size_t ws_size,
                              hipStream_t stream) {
  (void)in_sizes; (void)n_in; (void)out_size; (void)ws_size;
  const float* x     = (const float*)d_in[0];
  const float* w_lin = (const float*)d_in[1];
  const float* w_ih  = (const float*)d_in[3];
  const float* w_hh  = (const float*)d_in[4];
  const float* b_ih  = (const float*)d_in[5];
  const float* b_hh  = (const float*)d_in[6];
  float* out = (float*)d_out;  // [x_atn | x_enc] f32

  char* ws = (char*)d_ws;
  float* bias          = (float*)ws;                                 // 2 KB
  unsigned short* wihb = (unsigned short*)(ws + 4096);               // 128 KB
  unsigned short* whhb = (unsigned short*)(ws + 4096 + (1 << 17));   // 128 KB

  float* enc = out + (size_t)NB * TT * FF;

  k_prep<<<dim3(64), dim3(256), 0, stream>>>(w_ih, w_hh, b_ih, b_hh, wihb, whhb, bias);
  k_attn_xatn<<<dim3(NB), dim3(256), 0, stream>>>(x, w_lin, out);
  k_rnn_full<<<dim3(256), dim3(512), 0, stream>>>(whhb, wihb, bias, out, enc);
}

// Round 8
// 178.521 us; speedup vs baseline: 3.1681x; 1.1715x over previous
//
#include <hip/hip_runtime.h>
#include <hip/hip_bf16.h>

typedef __attribute__((ext_vector_type(8))) short bf16x8;
typedef __attribute__((ext_vector_type(4))) float f32x4;

#define NB 2048
#define TT 128   // T-1
#define FF 128
#define HH 128
#define NG 512   // 4*H

__device__ __forceinline__ unsigned short f2bf(float x) {
  union { float f; unsigned u; } v; v.f = x;
  unsigned r = (v.u + 0x7fffu + ((v.u >> 16) & 1u)) >> 16;
  return (unsigned short)r;
}
__device__ __forceinline__ unsigned cvtpk_bf16(float lo, float hi) {
  unsigned r;
  asm("v_cvt_pk_bf16_f32 %0, %1, %2" : "=v"(r) : "v"(lo), "v"(hi));
  return r;
}
__device__ __forceinline__ float frcp(float x) { return __builtin_amdgcn_rcpf(x); }
__device__ __forceinline__ float sigf(float x) { return frcp(1.f + __expf(-x)); }
__device__ __forceinline__ float tanh_(float x) {
  float e = __expf(-2.f * x);
  return (1.f - e) * frcp(1.f + e);
}
// XOR swizzle for 256B (128 bf16) rows: spreads 16B chunks across banks
__device__ __forceinline__ unsigned swzb(int row, int kbyte) {
  return (unsigned)(row * 256 + (kbyte ^ ((row & 7) << 4)));
}
// barrier that does NOT drain vmcnt (enc stores are fire-and-forget)
__device__ __forceinline__ void barrier_lds() {
  asm volatile("s_waitcnt lgkmcnt(0)" ::: "memory");
  __builtin_amdgcn_s_barrier();
  __builtin_amdgcn_sched_barrier(0);
}

// ------- K0: prep (w_ih, w_hh -> bf16; bias = b_ih + b_hh) -------------------
__global__ void k_prep(const float* __restrict__ w_ih, const float* __restrict__ w_hh,
                       const float* __restrict__ b_ih, const float* __restrict__ b_hh,
                       unsigned short* __restrict__ wihb, unsigned short* __restrict__ whhb,
                       float* __restrict__ bias) {
  int g = blockIdx.x * blockDim.x + threadIdx.x;
  int gs = gridDim.x * blockDim.x;
  for (int i = g; i < NG * FF; i += gs) {
    wihb[i] = f2bf(w_ih[i]);
    whhb[i] = f2bf(w_hh[i]);
  }
  if (g < NG) bias[g] = b_ih[g] + b_hh[g];
}

// -------- K1: single-pass a=softmax_f(sum_t x*wx); x_atn = a*x (f32 out) -----
// x tile (64 KB) cached in registers: 16 float4/thread. One global read of x.
__global__ __launch_bounds__(256) void k_attn_xatn(const float* __restrict__ x,
                                                   const float* __restrict__ w_lin,
                                                   float* __restrict__ out) {
  __shared__ float4 red[256];
  __shared__ float wxs[TT];
  __shared__ float4 aSh[32];
  int tid = threadIdx.x;
  int b = blockIdx.x;
  if (tid < TT) wxs[tid] = w_lin[2 * HH + tid];
  __syncthreads();
  const float4* xb4 = (const float4*)(x + (size_t)b * TT * FF);
  // thread tid owns chunks i4 = tid + 256k: t = i4>>5 = (tid>>5)+8k, f4 = tid&31
  float4 xv[16];
  float4 acc = {0.f, 0.f, 0.f, 0.f};
  int tbase = tid >> 5;
#pragma unroll
  for (int k = 0; k < 16; ++k) {
    xv[k] = xb4[tid + k * 256];
    float wt = wxs[tbase + k * 8];
    acc.x += xv[k].x * wt; acc.y += xv[k].y * wt;
    acc.z += xv[k].z * wt; acc.w += xv[k].w * wt;
  }
  red[tid] = acc;
  __syncthreads();
  if (tid < 64) {
    float4 a0 = red[tid], a1 = red[tid + 64], a2 = red[tid + 128], a3 = red[tid + 192];
    a0.x += a1.x + a2.x + a3.x; a0.y += a1.y + a2.y + a3.y;
    a0.z += a1.z + a2.z + a3.z; a0.w += a1.w + a2.w + a3.w;
    red[tid] = a0;
  }
  __syncthreads();
  if (tid < 32) {
    float4 s = red[tid], s2 = red[tid + 32];
    s.x += s2.x; s.y += s2.y; s.z += s2.z; s.w += s2.w;
    float m = fmaxf(fmaxf(s.x, s.y), fmaxf(s.z, s.w));
#pragma unroll
    for (int d = 1; d < 32; d <<= 1) m = fmaxf(m, __shfl_xor(m, d));
    float4 e;
    e.x = __expf(s.x - m); e.y = __expf(s.y - m);
    e.z = __expf(s.z - m); e.w = __expf(s.w - m);
    float sum = e.x + e.y + e.z + e.w;
#pragma unroll
    for (int d = 1; d < 32; d <<= 1) sum += __shfl_xor(sum, d);
    float inv = frcp(sum);
    e.x *= inv; e.y *= inv; e.z *= inv; e.w *= inv;
    aSh[tid] = e;
  }
  __syncthreads();
  float4 av = aSh[tid & 31];
  float4* ob4 = (float4*)(out + (size_t)b * TT * FF);
#pragma unroll
  for (int k = 0; k < 16; ++k) {
    float4 o;
    o.x = xv[k].x * av.x; o.y = xv[k].y * av.y;
    o.z = xv[k].z * av.z; o.w = xv[k].w * av.w;
    ob4[tid + k * 256] = o;
  }
}

// -------- K2: full recurrence, K=256 MFMA ([h | xa] @ [w_hh | w_ih]^T) -------
// 8 batch rows/block; LDS stores only the 8 real rows (lanes 8..15 of each
// 16-lane group broadcast-read row l&7). x-GEMM pipelined one step ahead and
// issued FIRST (hides h ds_read latency). setprio(1) around the MFMA cluster.
__global__ __launch_bounds__(512, 1) void k_rnn_full(const unsigned short* __restrict__ whhb,
                                                     const unsigned short* __restrict__ wihb,
                                                     const float* __restrict__ bias,
                                                     const float* __restrict__ xa,
                                                     float* __restrict__ enc) {
  __shared__ unsigned char hLds[2][2048];  // 8 rows x 128 bf16
  __shared__ unsigned char xLds[2][2048];
  int tid = threadIdx.x;
  int l = tid & 63, w = tid >> 6;
  int lg = l >> 4;
  bool low = (lg < 2);
  int b0 = blockIdx.x * 8;
  int kl = w * 16 + (l & 15);  // gate column k in [0,128)
  int ar = l & 7;              // LDS row this lane reads (broadcast for l&8)

  // B-fragments: per gate g, ks 0..3 = w_hh (K=h), ks 4..7 = w_ih (K=xa)
  bf16x8 Bf[4][8];
  f32x4 bv0, bv1, bv2, bv3;
  {
    float bc0 = bias[0 * 128 + kl], bc1 = bias[1 * 128 + kl];
    float bc2 = bias[2 * 128 + kl], bc3 = bias[3 * 128 + kl];
    bv0 = (f32x4){bc0, bc0, bc0, bc0};
    bv1 = (f32x4){bc1, bc1, bc1, bc1};
    bv2 = (f32x4){bc2, bc2, bc2, bc2};
    bv3 = (f32x4){bc3, bc3, bc3, bc3};
  }
#pragma unroll
  for (int g = 0; g < 4; ++g) {
    int n = g * 128 + kl;
#pragma unroll
    for (int ks = 0; ks < 4; ++ks) {
      Bf[g][ks]     = *(const bf16x8*)(whhb + (size_t)n * HH + ks * 32 + lg * 8);
      Bf[g][4 + ks] = *(const bf16x8*)(wihb + (size_t)n * FF + ks * 32 + lg * 8);
    }
  }
  // zero both h/x double-buffers (1024 dwords total)
  for (int i = tid; i < 512; i += 512) {
    ((unsigned*)hLds)[i] = 0u; ((unsigned*)hLds)[i + 512] = 0u;
    ((unsigned*)xLds)[i] = 0u; ((unsigned*)xLds)[i + 512] = 0u;
  }
  int srow = tid >> 6, sf = (tid & 63) * 2;
  const float* xrow = xa + (size_t)(b0 + srow) * TT * FF + sf;
  // prologue: stage xa(0) -> xLds[0]
  {
    float2 v = *(const float2*)xrow;
    *(unsigned*)(xLds[0] + swzb(srow, sf * 2)) = cvtpk_bf16(v.x, v.y);
  }
  barrier_lds();
  // xaccA = bias + x-gates(0); stage xa(1) -> xLds[1]
  f32x4 xaccA0, xaccA1, xaccA2, xaccA3;
  f32x4 xaccB0, xaccB1, xaccB2, xaccB3;
  {
    float2 v = *(const float2*)(xrow + FF);
    bf16x8 Ax[4];
#pragma unroll
    for (int ks = 0; ks < 4; ++ks)
      Ax[ks] = *(const bf16x8*)(xLds[0] + swzb(ar, ks * 64 + lg * 16));
    xaccA0 = bv0; xaccA1 = bv1; xaccA2 = bv2; xaccA3 = bv3;
#pragma unroll
    for (int ks = 0; ks < 4; ++ks) {
      xaccA0 = __builtin_amdgcn_mfma_f32_16x16x32_bf16(Ax[ks], Bf[0][4 + ks], xaccA0, 0, 0, 0);
      xaccA1 = __builtin_amdgcn_mfma_f32_16x16x32_bf16(Ax[ks], Bf[1][4 + ks], xaccA1, 0, 0, 0);
      xaccA2 = __builtin_amdgcn_mfma_f32_16x16x32_bf16(Ax[ks], Bf[2][4 + ks], xaccA2, 0, 0, 0);
      xaccA3 = __builtin_amdgcn_mfma_f32_16x16x32_bf16(Ax[ks], Bf[3][4 + ks], xaccA3, 0, 0, 0);
    }
    *(unsigned*)(xLds[1] + swzb(srow, sf * 2)) = cvtpk_bf16(v.x, v.y);
  }
  barrier_lds();

  int bq0 = ((lg & 1) << 2) | ((lg >> 1) << 1);  // 0,4,2,6
  float c0 = 0.f, c1 = 0.f;
  float* pA = enc + (size_t)(b0 + bq0) * TT * HH + kl;
  float* pB = enc + (size_t)(b0 + bq0 + 1) * TT * HH + kl;

#define RNN_BODY(tc, CUR, NXT, XU0, XU1, XU2, XU3, XN0, XN1, XN2, XN3)          \
  {                                                                              \
    float2 pv = *(const float2*)(xrow + (size_t)((tc) + 2) * FF);                \
    bf16x8 Ax[4], Ah[4];                                                         \
    _Pragma("unroll")                                                            \
    for (int ks = 0; ks < 4; ++ks)                                               \
      Ax[ks] = *(const bf16x8*)(xLds[NXT] + swzb(ar, ks * 64 + lg * 16));        \
    _Pragma("unroll")                                                            \
    for (int ks = 0; ks < 4; ++ks)                                               \
      Ah[ks] = *(const bf16x8*)(hLds[CUR] + swzb(ar, ks * 64 + lg * 16));        \
    __builtin_amdgcn_s_setprio(1);                                               \
    /* x-chain first (independent): hides Ah ds_read latency */                  \
    XN0 = bv0; XN1 = bv1; XN2 = bv2; XN3 = bv3;                                  \
    _Pragma("unroll")                                                            \
    for (int ks = 0; ks < 4; ++ks) {                                             \
      XN0 = __builtin_amdgcn_mfma_f32_16x16x32_bf16(Ax[ks], Bf[0][4+ks], XN0, 0,0,0);\
      XN1 = __builtin_amdgcn_mfma_f32_16x16x32_bf16(Ax[ks], Bf[1][4+ks], XN1, 0,0,0);\
      XN2 = __builtin_amdgcn_mfma_f32_16x16x32_bf16(Ax[ks], Bf[2][4+ks], XN2, 0,0,0);\
      XN3 = __builtin_amdgcn_mfma_f32_16x16x32_bf16(Ax[ks], Bf[3][4+ks], XN3, 0,0,0);\
    }                                                                            \
    /* h-chain accumulates onto (bias + x-gates) from prev step */               \
    f32x4 s0 = XU0, s1 = XU1, s2 = XU2, s3 = XU3;                                \
    _Pragma("unroll")                                                            \
    for (int ks = 0; ks < 4; ++ks) {                                             \
      s0 = __builtin_amdgcn_mfma_f32_16x16x32_bf16(Ah[ks], Bf[0][ks], s0, 0,0,0);\
      s1 = __builtin_amdgcn_mfma_f32_16x16x32_bf16(Ah[ks], Bf[1][ks], s1, 0,0,0);\
      s2 = __builtin_amdgcn_mfma_f32_16x16x32_bf16(Ah[ks], Bf[2][ks], s2, 0,0,0);\
      s3 = __builtin_amdgcn_mfma_f32_16x16x32_bf16(Ah[ks], Bf[3][ks], s3, 0,0,0);\
    }                                                                            \
    __builtin_amdgcn_s_setprio(0);                                               \
    float giA = low ? s0[0] : s0[2], giB = low ? s0[1] : s0[3];                  \
    float gfA = low ? s1[0] : s1[2], gfB = low ? s1[1] : s1[3];                  \
    float ggA = low ? s2[0] : s2[2], ggB = low ? s2[1] : s2[3];                  \
    float goA = low ? s3[0] : s3[2], goB = low ? s3[1] : s3[3];                  \
    float cnA = sigf(gfA) * c0 + sigf(giA) * tanh_(ggA);                         \
    float cnB = sigf(gfB) * c1 + sigf(giB) * tanh_(ggB);                         \
    c0 = cnA; c1 = cnB;                                                          \
    float hvA = sigf(goA) * tanh_(cnA);                                          \
    float hvB = sigf(goB) * tanh_(cnB);                                          \
    unsigned hp = cvtpk_bf16(hvA, hvB);                                          \
    unsigned hq = hp >> 16;                                                      \
    *(unsigned short*)(hLds[NXT] + swzb(bq0, kl * 2)) = (unsigned short)hp;      \
    *(unsigned short*)(hLds[NXT] + swzb(bq0 + 1, kl * 2)) = (unsigned short)hq;  \
    pA[(size_t)(tc) * HH] = hvA;                                                 \
    pB[(size_t)(tc) * HH] = hvB;                                                 \
    *(unsigned*)(xLds[CUR] + swzb(srow, sf * 2)) = cvtpk_bf16(pv.x, pv.y);       \
    barrier_lds();                                                               \
  }

  for (int t = 0; t < TT; t += 2) {
    RNN_BODY(t,     0, 1, xaccA0, xaccA1, xaccA2, xaccA3, xaccB0, xaccB1, xaccB2, xaccB3)
    RNN_BODY(t + 1, 1, 0, xaccB0, xaccB1, xaccB2, xaccB3, xaccA0, xaccA1, xaccA2, xaccA3)
  }
#undef RNN_BODY
}

extern "C" void kernel_launch(void* const* d_in, const int* in_sizes, int n_in,
                              void* d_out, int out_size, void* d_ws, size_t ws_size,
                              hipStream_t stream) {
  (void)in_sizes; (void)n_in; (void)out_size; (void)ws_size;
  const float* x     = (const float*)d_in[0];
  const float* w_lin = (const float*)d_in[1];
  const float* w_ih  = (const float*)d_in[3];
  const float* w_hh  = (const float*)d_in[4];
  const float* b_ih  = (const float*)d_in[5];
  const float* b_hh  = (const float*)d_in[6];
  float* out = (float*)d_out;  // [x_atn | x_enc] f32

  char* ws = (char*)d_ws;
  float* bias          = (float*)ws;                                 // 2 KB
  unsigned short* wihb = (unsigned short*)(ws + 4096);               // 128 KB
  unsigned short* whhb = (unsigned short*)(ws + 4096 + (1 << 17));   // 128 KB

  float* enc = out + (size_t)NB * TT * FF;

  k_prep<<<dim3(64), dim3(256), 0, stream>>>(w_ih, w_hh, b_ih, b_hh, wihb, whhb, bias);
  k_attn_xatn<<<dim3(NB), dim3(256), 0, stream>>>(x, w_lin, out);
  k_rnn_full<<<dim3(256), dim3(512), 0, stream>>>(whhb, wihb, bias, out, enc);
}

// Round 9
// 175.326 us; speedup vs baseline: 3.2259x; 1.0182x over previous
//
#include <hip/hip_runtime.h>
#include <hip/hip_bf16.h>

typedef __attribute__((ext_vector_type(8))) short bf16x8;
typedef __attribute__((ext_vector_type(4))) float f32x4;

#define NB 2048
#define TT 128   // T-1
#define FF 128
#define HH 128
#define NG 512   // 4*H

__device__ __forceinline__ unsigned short f2bf(float x) {
  union { float f; unsigned u; } v; v.f = x;
  unsigned r = (v.u + 0x7fffu + ((v.u >> 16) & 1u)) >> 16;
  return (unsigned short)r;
}
__device__ __forceinline__ unsigned cvtpk_bf16(float lo, float hi) {
  unsigned r;
  asm("v_cvt_pk_bf16_f32 %0, %1, %2" : "=v"(r) : "v"(lo), "v"(hi));
  return r;
}
__device__ __forceinline__ float frcp(float x) { return __builtin_amdgcn_rcpf(x); }
__device__ __forceinline__ float sigf(float x) { return frcp(1.f + __expf(-x)); }
__device__ __forceinline__ float tanh_(float x) {
  float e = __expf(-2.f * x);
  return (1.f - e) * frcp(1.f + e);
}
// XOR swizzle for 256B (128 bf16) rows: spreads 16B chunks across banks
__device__ __forceinline__ unsigned swzb(int row, int kbyte) {
  return (unsigned)(row * 256 + (kbyte ^ ((row & 7) << 4)));
}
// barrier that does NOT drain vmcnt; single asm so no memory op crosses,
// but register-only VALU may be scheduled across it.
__device__ __forceinline__ void barrier_lds() {
  asm volatile("s_waitcnt lgkmcnt(0)\n\ts_barrier" ::: "memory");
}

// ------- K0: prep (w_ih, w_hh -> bf16; bias = b_ih + b_hh) -------------------
__global__ void k_prep(const float* __restrict__ w_ih, const float* __restrict__ w_hh,
                       const float* __restrict__ b_ih, const float* __restrict__ b_hh,
                       unsigned short* __restrict__ wihb, unsigned short* __restrict__ whhb,
                       float* __restrict__ bias) {
  int g = blockIdx.x * blockDim.x + threadIdx.x;
  int gs = gridDim.x * blockDim.x;
  for (int i = g; i < NG * FF; i += gs) {
    wihb[i] = f2bf(w_ih[i]);
    whhb[i] = f2bf(w_hh[i]);
  }
  if (g < NG) bias[g] = b_ih[g] + b_hh[g];
}

// -------- K1: single-pass a=softmax_f(sum_t x*wx); x_atn = a*x (f32 out) -----
__global__ __launch_bounds__(256) void k_attn_xatn(const float* __restrict__ x,
                                                   const float* __restrict__ w_lin,
                                                   float* __restrict__ out) {
  __shared__ float4 red[256];
  __shared__ float wxs[TT];
  __shared__ float4 aSh[32];
  int tid = threadIdx.x;
  int b = blockIdx.x;
  if (tid < TT) wxs[tid] = w_lin[2 * HH + tid];
  __syncthreads();
  const float4* xb4 = (const float4*)(x + (size_t)b * TT * FF);
  float4 xv[16];
  float4 acc = {0.f, 0.f, 0.f, 0.f};
  int tbase = tid >> 5;
#pragma unroll
  for (int k = 0; k < 16; ++k) {
    xv[k] = xb4[tid + k * 256];
    float wt = wxs[tbase + k * 8];
    acc.x += xv[k].x * wt; acc.y += xv[k].y * wt;
    acc.z += xv[k].z * wt; acc.w += xv[k].w * wt;
  }
  red[tid] = acc;
  __syncthreads();
  if (tid < 64) {
    float4 a0 = red[tid], a1 = red[tid + 64], a2 = red[tid + 128], a3 = red[tid + 192];
    a0.x += a1.x + a2.x + a3.x; a0.y += a1.y + a2.y + a3.y;
    a0.z += a1.z + a2.z + a3.z; a0.w += a1.w + a2.w + a3.w;
    red[tid] = a0;
  }
  __syncthreads();
  if (tid < 32) {
    float4 s = red[tid], s2 = red[tid + 32];
    s.x += s2.x; s.y += s2.y; s.z += s2.z; s.w += s2.w;
    float m = fmaxf(fmaxf(s.x, s.y), fmaxf(s.z, s.w));
#pragma unroll
    for (int d = 1; d < 32; d <<= 1) m = fmaxf(m, __shfl_xor(m, d));
    float4 e;
    e.x = __expf(s.x - m); e.y = __expf(s.y - m);
    e.z = __expf(s.z - m); e.w = __expf(s.w - m);
    float sum = e.x + e.y + e.z + e.w;
#pragma unroll
    for (int d = 1; d < 32; d <<= 1) sum += __shfl_xor(sum, d);
    float inv = frcp(sum);
    e.x *= inv; e.y *= inv; e.z *= inv; e.w *= inv;
    aSh[tid] = e;
  }
  __syncthreads();
  float4 av = aSh[tid & 31];
  float4* ob4 = (float4*)(out + (size_t)b * TT * FF);
#pragma unroll
  for (int k = 0; k < 16; ++k) {
    float4 o;
    o.x = xv[k].x * av.x; o.y = xv[k].y * av.y;
    o.z = xv[k].z * av.z; o.w = xv[k].w * av.w;
    ob4[tid + k * 256] = o;
  }
}

// -------- K2: full recurrence, K=256 MFMA ([h | xa] @ [w_hh | w_ih]^T) -------
// 8 batch rows/block; dedup'd LDS (broadcast reads). h-MFMA issued first;
// x-MFMA fills the pointwise shadow. xa stage-write deferred one body
// (cross-barrier slack). No setprio, no sched_barrier.
__global__ __launch_bounds__(512, 1) void k_rnn_full(const unsigned short* __restrict__ whhb,
                                                     const unsigned short* __restrict__ wihb,
                                                     const float* __restrict__ bias,
                                                     const float* __restrict__ xa,
                                                     float* __restrict__ enc) {
  __shared__ unsigned char hLds[2][2048];  // 8 rows x 128 bf16
  __shared__ unsigned char xLds[2][2048];
  int tid = threadIdx.x;
  int l = tid & 63, w = tid >> 6;
  int lg = l >> 4;
  bool low = (lg < 2);
  int b0 = blockIdx.x * 8;
  int kl = w * 16 + (l & 15);  // gate column k in [0,128)
  int ar = l & 7;              // LDS row this lane reads (broadcast for l&8)

  // B-fragments: per gate g, ks 0..3 = w_hh (K=h), ks 4..7 = w_ih (K=xa)
  bf16x8 Bf[4][8];
  f32x4 bv0, bv1, bv2, bv3;
  {
    float bc0 = bias[0 * 128 + kl], bc1 = bias[1 * 128 + kl];
    float bc2 = bias[2 * 128 + kl], bc3 = bias[3 * 128 + kl];
    bv0 = (f32x4){bc0, bc0, bc0, bc0};
    bv1 = (f32x4){bc1, bc1, bc1, bc1};
    bv2 = (f32x4){bc2, bc2, bc2, bc2};
    bv3 = (f32x4){bc3, bc3, bc3, bc3};
  }
#pragma unroll
  for (int g = 0; g < 4; ++g) {
    int n = g * 128 + kl;
#pragma unroll
    for (int ks = 0; ks < 4; ++ks) {
      Bf[g][ks]     = *(const bf16x8*)(whhb + (size_t)n * HH + ks * 32 + lg * 8);
      Bf[g][4 + ks] = *(const bf16x8*)(wihb + (size_t)n * FF + ks * 32 + lg * 8);
    }
  }
  // zero both h/x double-buffers
  for (int i = tid; i < 512; i += 512) {
    ((unsigned*)hLds)[i] = 0u; ((unsigned*)hLds)[i + 512] = 0u;
    ((unsigned*)xLds)[i] = 0u; ((unsigned*)xLds)[i + 512] = 0u;
  }
  int srow = tid >> 6, sf = (tid & 63) * 2;
  const float* xrow = xa + (size_t)(b0 + srow) * TT * FF + sf;
  // prologue: stage xa(0) -> xLds[0]
  {
    float2 v = *(const float2*)xrow;
    *(unsigned*)(xLds[0] + swzb(srow, sf * 2)) = cvtpk_bf16(v.x, v.y);
  }
  barrier_lds();
  // xaccA = bias + x-gates(0); stage xa(1) -> xLds[1]; preload pv = xa(2)
  f32x4 xaccA0, xaccA1, xaccA2, xaccA3;
  f32x4 xaccB0, xaccB1, xaccB2, xaccB3;
  float2 pv;
  {
    float2 v = *(const float2*)(xrow + FF);
    bf16x8 Ax[4];
#pragma unroll
    for (int ks = 0; ks < 4; ++ks)
      Ax[ks] = *(const bf16x8*)(xLds[0] + swzb(ar, ks * 64 + lg * 16));
    xaccA0 = bv0; xaccA1 = bv1; xaccA2 = bv2; xaccA3 = bv3;
#pragma unroll
    for (int ks = 0; ks < 4; ++ks) {
      xaccA0 = __builtin_amdgcn_mfma_f32_16x16x32_bf16(Ax[ks], Bf[0][4 + ks], xaccA0, 0, 0, 0);
      xaccA1 = __builtin_amdgcn_mfma_f32_16x16x32_bf16(Ax[ks], Bf[1][4 + ks], xaccA1, 0, 0, 0);
      xaccA2 = __builtin_amdgcn_mfma_f32_16x16x32_bf16(Ax[ks], Bf[2][4 + ks], xaccA2, 0, 0, 0);
      xaccA3 = __builtin_amdgcn_mfma_f32_16x16x32_bf16(Ax[ks], Bf[3][4 + ks], xaccA3, 0, 0, 0);
    }
    *(unsigned*)(xLds[1] + swzb(srow, sf * 2)) = cvtpk_bf16(v.x, v.y);
    pv = *(const float2*)(xrow + 2 * FF);
  }
  barrier_lds();

  int bq0 = ((lg & 1) << 2) | ((lg >> 1) << 1);  // 0,4,2,6
  float c0 = 0.f, c1 = 0.f;
  float* pA = enc + (size_t)(b0 + bq0) * TT * HH + kl;
  float* pB = enc + (size_t)(b0 + bq0 + 1) * TT * HH + kl;

#define RNN_BODY(tc, CUR, NXT, XU0, XU1, XU2, XU3, XN0, XN1, XN2, XN3)          \
  {                                                                              \
    /* deferred stage-write: pv holds xa(tc+2), goes into buffer CUR */          \
    *(unsigned*)(xLds[CUR] + swzb(srow, sf * 2)) = cvtpk_bf16(pv.x, pv.y);       \
    pv = *(const float2*)(xrow + (size_t)((tc) + 3) * FF);                       \
    bf16x8 Ah[4], Ax[4];                                                         \
    _Pragma("unroll")                                                            \
    for (int ks = 0; ks < 4; ++ks)                                               \
      Ah[ks] = *(const bf16x8*)(hLds[CUR] + swzb(ar, ks * 64 + lg * 16));        \
    _Pragma("unroll")                                                            \
    for (int ks = 0; ks < 4; ++ks)                                               \
      Ax[ks] = *(const bf16x8*)(xLds[NXT] + swzb(ar, ks * 64 + lg * 16));        \
    /* h-chain first: accumulates onto (bias + x-gates) from prev step */        \
    f32x4 s0 = XU0, s1 = XU1, s2 = XU2, s3 = XU3;                                \
    _Pragma("unroll")                                                            \
    for (int ks = 0; ks < 4; ++ks) {                                             \
      s0 = __builtin_amdgcn_mfma_f32_16x16x32_bf16(Ah[ks], Bf[0][ks], s0, 0,0,0);\
      s1 = __builtin_amdgcn_mfma_f32_16x16x32_bf16(Ah[ks], Bf[1][ks], s1, 0,0,0);\
      s2 = __builtin_amdgcn_mfma_f32_16x16x32_bf16(Ah[ks], Bf[2][ks], s2, 0,0,0);\
      s3 = __builtin_amdgcn_mfma_f32_16x16x32_bf16(Ah[ks], Bf[3][ks], s3, 0,0,0);\
    }                                                                            \
    /* x-chain (independent): issues in the shadow of the pointwise below */     \
    XN0 = bv0; XN1 = bv1; XN2 = bv2; XN3 = bv3;                                  \
    _Pragma("unroll")                                                            \
    for (int ks = 0; ks < 4; ++ks) {                                             \
      XN0 = __builtin_amdgcn_mfma_f32_16x16x32_bf16(Ax[ks], Bf[0][4+ks], XN0, 0,0,0);\
      XN1 = __builtin_amdgcn_mfma_f32_16x16x32_bf16(Ax[ks], Bf[1][4+ks], XN1, 0,0,0);\
      XN2 = __builtin_amdgcn_mfma_f32_16x16x32_bf16(Ax[ks], Bf[2][4+ks], XN2, 0,0,0);\
      XN3 = __builtin_amdgcn_mfma_f32_16x16x32_bf16(Ax[ks], Bf[3][4+ks], XN3, 0,0,0);\
    }                                                                            \
    float giA = low ? s0[0] : s0[2], giB = low ? s0[1] : s0[3];                  \
    float gfA = low ? s1[0] : s1[2], gfB = low ? s1[1] : s1[3];                  \
    float ggA = low ? s2[0] : s2[2], ggB = low ? s2[1] : s2[3];                  \
    float goA = low ? s3[0] : s3[2], goB = low ? s3[1] : s3[3];                  \
    float cnA = sigf(gfA) * c0 + sigf(giA) * tanh_(ggA);                         \
    float cnB = sigf(gfB) * c1 + sigf(giB) * tanh_(ggB);                         \
    c0 = cnA; c1 = cnB;                                                          \
    float hvA = sigf(goA) * tanh_(cnA);                                          \
    float hvB = sigf(goB) * tanh_(cnB);                                          \
    unsigned hp = cvtpk_bf16(hvA, hvB);                                          \
    unsigned hq = hp >> 16;                                                      \
    *(unsigned short*)(hLds[NXT] + swzb(bq0, kl * 2)) = (unsigned short)hp;      \
    *(unsigned short*)(hLds[NXT] + swzb(bq0 + 1, kl * 2)) = (unsigned short)hq;  \
    pA[(size_t)(tc) * HH] = hvA;                                                 \
    pB[(size_t)(tc) * HH] = hvB;                                                 \
    barrier_lds();                                                               \
  }

  for (int t = 0; t < TT; t += 2) {
    RNN_BODY(t,     0, 1, xaccA0, xaccA1, xaccA2, xaccA3, xaccB0, xaccB1, xaccB2, xaccB3)
    RNN_BODY(t + 1, 1, 0, xaccB0, xaccB1, xaccB2, xaccB3, xaccA0, xaccA1, xaccA2, xaccA3)
  }
#undef RNN_BODY
}

extern "C" void kernel_launch(void* const* d_in, const int* in_sizes, int n_in,
                              void* d_out, int out_size, void* d_ws, size_t ws_size,
                              hipStream_t stream) {
  (void)in_sizes; (void)n_in; (void)out_size; (void)ws_size;
  const float* x     = (const float*)d_in[0];
  const float* w_lin = (const float*)d_in[1];
  const float* w_ih  = (const float*)d_in[3];
  const float* w_hh  = (const float*)d_in[4];
  const float* b_ih  = (const float*)d_in[5];
  const float* b_hh  = (const float*)d_in[6];
  float* out = (float*)d_out;  // [x_atn | x_enc] f32

  char* ws = (char*)d_ws;
  float* bias          = (float*)ws;                                 // 2 KB
  unsigned short* wihb = (unsigned short*)(ws + 4096);               // 128 KB
  unsigned short* whhb = (unsigned short*)(ws + 4096 + (1 << 17));   // 128 KB

  float* enc = out + (size_t)NB * TT * FF;

  k_prep<<<dim3(64), dim3(256), 0, stream>>>(w_ih, w_hh, b_ih, b_hh, wihb, whhb, bias);
  k_attn_xatn<<<dim3(NB), dim3(256), 0, stream>>>(x, w_lin, out);
  k_rnn_full<<<dim3(256), dim3(512), 0, stream>>>(whhb, wihb, bias, out, enc);
}